// Round 12
// baseline (1405.680 us; speedup 1.0000x reference)
//
#include <hip/hip_runtime.h>

// EncodeProcessDecode (GNS): N=10000 nodes, E=100000 edges, S=10 steps, L=H=128.
// Round 12: R9 base + edge_step double-buffered K=64 weight staging (2x[128][68]
// buffers = same 52.7KB LDS, 3 blocks/CU). Stage of chunk c+1 overlaps compute of
// chunk c; stage->use stall leaves the critical path. R8/R11 lesson respected:
// no registers held across MFMA, no VGPR/LDS growth. Node step = R9 fused-CSR.

#define NN 10000
#define NE 100000
#define STEPS 10
#define NODE_F 30
#define EDGE_F 4
#define L 128
#define AP 132   // fp32 helper LDS stride (encoder-node / decoder)
#define BP 36

#define WS_STRIDE 136   // full-K LDS row stride (node/encoder)
#define AB_STRIDE 136
#define WH_STRIDE 68    // half-K (64+4) stride, edge double-buffer

typedef __bf16 bf16x8 __attribute__((ext_vector_type(8)));
typedef float f32x4 __attribute__((ext_vector_type(4)));

__device__ __forceinline__ unsigned short f2bf(float f) {
  __bf16 b = (__bf16)f;
  return __builtin_bit_cast(unsigned short, b);
}
__device__ __forceinline__ float bf2f(unsigned short u) {
  return __builtin_bit_cast(float, (unsigned)u << 16);
}

// ================= staging =================

// full 128k x 128n section (node/encoder kernels)
__device__ __forceinline__ void stage_W(unsigned short* __restrict__ Ws,
                                        const unsigned short* __restrict__ Wt,
                                        int K, int sec, int tid) {
#pragma unroll
  for (int p = 0; p < 8; ++p) {
    int u = tid + p * 256;
    int n = u >> 4, kk = u & 15;
    uint4 v = *(const uint4*)(Wt + (size_t)n * K + sec * 128 + kk * 8);
    *(uint4*)&Ws[n * WS_STRIDE + kk * 8] = v;
  }
}

// half: 64k x 128n chunk into [n][WH_STRIDE] buffer (edge kernel)
__device__ __forceinline__ void stage64(unsigned short* __restrict__ Ws,
                                        const unsigned short* __restrict__ Wt,
                                        int K, int k0, int tid) {
#pragma unroll
  for (int p = 0; p < 4; ++p) {
    int u = tid + p * 256;          // < 1024
    int n = u >> 3, k8 = u & 7;     // n 0..127, 8 bf16 per thread-slot
    uint4 v = *(const uint4*)(Wt + (size_t)n * K + k0 + k8 * 8);
    *(uint4*)&Ws[n * WH_STRIDE + k8 * 8] = v;
  }
}

// ================= MFMA helpers (2x4: wave tile 32x64) =================

__device__ __forceinline__ void init_acc(f32x4 acc[2][4], const float* __restrict__ b,
                                         int wcol, int l16) {
#pragma unroll
  for (int j = 0; j < 4; ++j) {
    float bv = b[wcol + j * 16 + l16];
#pragma unroll
    for (int i = 0; i < 2; ++i) acc[i][j] = f32x4{bv, bv, bv, bv};
  }
}

__device__ __forceinline__ void init_acc_v(f32x4 acc[2][4], const float bv[4]) {
#pragma unroll
  for (int j = 0; j < 4; ++j) {
    f32x4 b = {bv[j], bv[j], bv[j], bv[j]};
#pragma unroll
    for (int i = 0; i < 2; ++i) acc[i][j] = b;
  }
}

// K=64 chunk, A from global bf16 rows (+koff), B from half buffer.
__device__ __forceinline__ void gemm64_g(const unsigned short* __restrict__ ap0,
                                         const unsigned short* __restrict__ ap1,
                                         int koff, const unsigned short* __restrict__ Ws,
                                         f32x4 acc[2][4], int wcol, int l4, int l16) {
#pragma unroll
  for (int kk = 0; kk < 2; ++kk) {
    bf16x8 af[2];
    af[0] = *(const bf16x8*)(ap0 + koff + kk * 32 + l4 * 8);
    af[1] = *(const bf16x8*)(ap1 + koff + kk * 32 + l4 * 8);
#pragma unroll
    for (int j = 0; j < 4; ++j) {
      bf16x8 bv = *(const bf16x8*)&Ws[(wcol + j * 16 + l16) * WH_STRIDE + kk * 32 + l4 * 8];
#pragma unroll
      for (int i = 0; i < 2; ++i)
        acc[i][j] = __builtin_amdgcn_mfma_f32_16x16x32_bf16(af[i], bv, acc[i][j], 0, 0, 0);
    }
  }
}

// K=64 chunk, A from Ab LDS (+koff), B from half buffer.
__device__ __forceinline__ void gemm64_l(const unsigned short* __restrict__ Ab, int koff,
                                         const unsigned short* __restrict__ Ws,
                                         f32x4 acc[2][4], int wrow, int wcol, int l4, int l16) {
#pragma unroll
  for (int kk = 0; kk < 2; ++kk) {
    bf16x8 af[2];
#pragma unroll
    for (int i = 0; i < 2; ++i)
      af[i] = *(const bf16x8*)&Ab[(wrow + i * 16 + l16) * AB_STRIDE + koff + kk * 32 + l4 * 8];
#pragma unroll
    for (int j = 0; j < 4; ++j) {
      bf16x8 bv = *(const bf16x8*)&Ws[(wcol + j * 16 + l16) * WH_STRIDE + kk * 32 + l4 * 8];
#pragma unroll
      for (int i = 0; i < 2; ++i)
        acc[i][j] = __builtin_amdgcn_mfma_f32_16x16x32_bf16(af[i], bv, acc[i][j], 0, 0, 0);
    }
  }
}

// full-K variants (node/encoder kernels)
__device__ __forceinline__ void layer_gbf(const unsigned short* __restrict__ ap0,
                                          const unsigned short* __restrict__ ap1,
                                          const unsigned short* __restrict__ Ws,
                                          f32x4 acc[2][4], int wcol, int l4, int l16) {
#pragma unroll
  for (int kk = 0; kk < 4; ++kk) {
    bf16x8 af[2];
    af[0] = *(const bf16x8*)(ap0 + kk * 32 + l4 * 8);
    af[1] = *(const bf16x8*)(ap1 + kk * 32 + l4 * 8);
#pragma unroll
    for (int j = 0; j < 4; ++j) {
      bf16x8 bv = *(const bf16x8*)&Ws[(wcol + j * 16 + l16) * WS_STRIDE + kk * 32 + l4 * 8];
#pragma unroll
      for (int i = 0; i < 2; ++i)
        acc[i][j] = __builtin_amdgcn_mfma_f32_16x16x32_bf16(af[i], bv, acc[i][j], 0, 0, 0);
    }
  }
}

__device__ __forceinline__ void layer_lds(const unsigned short* __restrict__ Ab,
                                          const unsigned short* __restrict__ Ws,
                                          f32x4 acc[2][4], int wrow, int wcol, int l4, int l16) {
#pragma unroll
  for (int kk = 0; kk < 4; ++kk) {
    bf16x8 af[2];
#pragma unroll
    for (int i = 0; i < 2; ++i)
      af[i] = *(const bf16x8*)&Ab[(wrow + i * 16 + l16) * AB_STRIDE + kk * 32 + l4 * 8];
#pragma unroll
    for (int j = 0; j < 4; ++j) {
      bf16x8 bv = *(const bf16x8*)&Ws[(wcol + j * 16 + l16) * WS_STRIDE + kk * 32 + l4 * 8];
#pragma unroll
      for (int i = 0; i < 2; ++i)
        acc[i][j] = __builtin_amdgcn_mfma_f32_16x16x32_bf16(af[i], bv, acc[i][j], 0, 0, 0);
    }
  }
}

__device__ __forceinline__ void relu_to_Ab(unsigned short* __restrict__ Ab, f32x4 acc[2][4],
                                           int wrow, int wcol, int l4, int l16) {
#pragma unroll
  for (int i = 0; i < 2; ++i)
#pragma unroll
    for (int j = 0; j < 4; ++j)
#pragma unroll
      for (int r = 0; r < 4; ++r) {
        int row = wrow + i * 16 + l4 * 4 + r;
        int col = wcol + j * 16 + l16;
        Ab[row * AB_STRIDE + col] = f2bf(fmaxf(acc[i][j][r], 0.f));
      }
}

__device__ __forceinline__ void ln_partials(const f32x4 acc[2][4], float ps[2][4], float ps2[2][4]) {
#pragma unroll
  for (int i = 0; i < 2; ++i)
#pragma unroll
    for (int r = 0; r < 4; ++r) {
      float s = 0.f, s2 = 0.f;
#pragma unroll
      for (int j = 0; j < 4; ++j) { float v = acc[i][j][r]; s += v; s2 += v * v; }
#pragma unroll
      for (int off = 1; off < 16; off <<= 1) {
        s += __shfl_xor(s, off, 64);
        s2 += __shfl_xor(s2, off, 64);
      }
      ps[i][r] = s; ps2[i][r] = s2;
    }
}

// ================= CSR prep =================

__global__ __launch_bounds__(256) void deg_kernel(const int* __restrict__ ei, int* __restrict__ cnt) {
  int e = blockIdx.x * 256 + threadIdx.x;
  if (e < NE) atomicAdd(&cnt[ei[NE + e]], 1);
}

__global__ __launch_bounds__(256) void scan_kernel(const int* __restrict__ cnt,
                                                   int* __restrict__ off, int* __restrict__ cur) {
  __shared__ int sums[256];
  int t = threadIdx.x;
  int base = t * 40;   // 256*40 = 10240 >= NN
  int local = 0;
  for (int i = 0; i < 40; ++i) { int n = base + i; if (n < NN) local += cnt[n]; }
  sums[t] = local;
  __syncthreads();
  int val = local;
  for (int d = 1; d < 256; d <<= 1) {
    int add = (t >= d) ? sums[t - d] : 0;
    __syncthreads();
    sums[t] += add;
    __syncthreads();
  }
  int run = sums[t] - val;
  for (int i = 0; i < 40; ++i) {
    int n = base + i;
    if (n < NN) { off[n] = run; cur[n] = run; run += cnt[n]; }
  }
  if (t == 255) off[NN] = sums[255];
}

__global__ __launch_bounds__(256) void scatter_kernel(const int* __restrict__ ei,
                                                      int* __restrict__ cur, int* __restrict__ eid) {
  int e = blockIdx.x * 256 + threadIdx.x;
  if (e < NE) { int p = atomicAdd(&cur[ei[NE + e]], 1); eid[p] = e; }
}

// ================= edge step: double-buffered K=64 pipeline =================

__global__ __launch_bounds__(256) void edge_step_mfma(
    const unsigned short* __restrict__ hx_bf, unsigned short* __restrict__ he_bf,
    unsigned short* __restrict__ ue_bf,
    const int* __restrict__ ei,
    const unsigned short* __restrict__ W0t, const float* __restrict__ b0,
    const unsigned short* __restrict__ W1t, const float* __restrict__ b1,
    const unsigned short* __restrict__ W2t, const float* __restrict__ b2,
    const float* __restrict__ g, const float* __restrict__ bt) {
  __shared__ __align__(16) unsigned short WsA[128 * WH_STRIDE];  // 17.4 KB
  __shared__ __align__(16) unsigned short WsB[128 * WH_STRIDE];  // 17.4 KB
  __shared__ __align__(16) unsigned short Ab[64 * AB_STRIDE];    // 17.4 KB
  __shared__ int sidx[64], didx[64];
  int tid = threadIdx.x;
  int w = tid >> 6, lane = tid & 63;
  int l4 = lane >> 4, l16 = lane & 15;
  int wrow = (w >> 1) * 32, wcol = (w & 1) * 64;
  int e0 = blockIdx.x * 64;
  if (tid < 64) {
    int e = min(e0 + tid, NE - 1);
    sidx[tid] = ei[e];
    didx[tid] = ei[NE + e];
  }
  float bv0[4], bv1[4], bv2[4], gv[4], btv[4];
#pragma unroll
  for (int j = 0; j < 4; ++j) {
    int c = wcol + j * 16 + l16;
    bv0[j] = b0[c]; bv1[j] = b1[c]; bv2[j] = b2[c]; gv[j] = g[c]; btv[j] = bt[c];
  }
  f32x4 acc[2][4];
  init_acc_v(acc, bv0);
  stage64(WsA, W0t, 384, 0, tid);            // c0 in flight
  __syncthreads();                           // WsA(c0) + idx ready

  const unsigned short *asrc[2], *adst[2], *ahe[2];
#pragma unroll
  for (int i = 0; i < 2; ++i) {
    int r = wrow + i * 16 + l16;
    asrc[i] = hx_bf + (size_t)sidx[r] * L;
    adst[i] = hx_bf + (size_t)didx[r] * L;
    ahe[i]  = he_bf + (size_t)min(e0 + r, NE - 1) * L;
  }
  // ---- layer0: 6 chunks (src k0-63, src k64-127, dst, dst, he, he) ----
  stage64(WsB, W0t, 384, 64, tid);           // c1
  gemm64_g(asrc[0], asrc[1], 0, WsA, acc, wcol, l4, l16);
  __syncthreads();
  stage64(WsA, W0t, 384, 128, tid);          // c2
  gemm64_g(asrc[0], asrc[1], 64, WsB, acc, wcol, l4, l16);
  __syncthreads();
  stage64(WsB, W0t, 384, 192, tid);          // c3
  gemm64_g(adst[0], adst[1], 0, WsA, acc, wcol, l4, l16);
  __syncthreads();
  stage64(WsA, W0t, 384, 256, tid);          // c4
  gemm64_g(adst[0], adst[1], 64, WsB, acc, wcol, l4, l16);
  __syncthreads();
  stage64(WsB, W0t, 384, 320, tid);          // c5
  gemm64_g(ahe[0], ahe[1], 0, WsA, acc, wcol, l4, l16);
  __syncthreads();
  stage64(WsA, W1t, 128, 0, tid);            // W1 chunk0
  gemm64_g(ahe[0], ahe[1], 64, WsB, acc, wcol, l4, l16);
  relu_to_Ab(Ab, acc, wrow, wcol, l4, l16);  // Ab first write, no prior readers
  init_acc_v(acc, bv1);
  __syncthreads();                           // WsA(W1c0) + Ab(l0) visible
  // ---- layer1: 2 chunks ----
  stage64(WsB, W1t, 128, 64, tid);           // W1 chunk1
  gemm64_l(Ab, 0, WsA, acc, wrow, wcol, l4, l16);
  __syncthreads();
  stage64(WsA, W2t, 128, 0, tid);            // W2 chunk0
  gemm64_l(Ab, 64, WsB, acc, wrow, wcol, l4, l16);
  __syncthreads();                           // all waves done reading Ab(l0)
  relu_to_Ab(Ab, acc, wrow, wcol, l4, l16);  // l1 out
  init_acc_v(acc, bv2);
  __syncthreads();                           // Ab(l1) + WsA(W2c0) visible
  // ---- layer2: 2 chunks ----
  stage64(WsB, W2t, 128, 64, tid);           // W2 chunk1
  gemm64_l(Ab, 0, WsA, acc, wrow, wcol, l4, l16);
  __syncthreads();                           // WsA reads done (red overlays WsA)
  gemm64_l(Ab, 64, WsB, acc, wrow, wcol, l4, l16);
  // ---- LayerNorm ----
  float ps[2][4], ps2[2][4];
  ln_partials(acc, ps, ps2);
  float* red = (float*)WsA;                  // [2 halves][64 rows][2]
  if (l16 == 0) {
#pragma unroll
    for (int i = 0; i < 2; ++i)
#pragma unroll
      for (int r = 0; r < 4; ++r) {
        int row = wrow + i * 16 + l4 * 4 + r;
        red[(w & 1) * 128 + row * 2 + 0] = ps[i][r];
        red[(w & 1) * 128 + row * 2 + 1] = ps2[i][r];
      }
  }
  __syncthreads();                           // red ready
#pragma unroll
  for (int i = 0; i < 2; ++i)
#pragma unroll
    for (int r = 0; r < 4; ++r) {
      int row = wrow + i * 16 + l4 * 4 + r;
      float s  = red[row * 2]     + red[128 + row * 2];
      float s2 = red[row * 2 + 1] + red[128 + row * 2 + 1];
      float m = s * (1.f / 128.f);
      float inv = rsqrtf(s2 * (1.f / 128.f) - m * m + 1e-5f);
      int e = e0 + row;
      if (e < NE) {
        size_t hoff = (size_t)e * L;
#pragma unroll
        for (int j = 0; j < 4; ++j) {
          int col = wcol + j * 16 + l16;
          float u = (acc[i][j][r] - m) * inv * gv[j] + btv[j];
          unsigned short old = he_bf[hoff + col];
          he_bf[hoff + col] = f2bf(bf2f(old) + u);
          ue_bf[hoff + col] = f2bf(u);
        }
      }
    }
}

// ================= node step: fused CSR aggregation (R9) =================

__global__ __launch_bounds__(256) void node_step_mfma(
    float* __restrict__ hx, unsigned short* __restrict__ hx_bf,
    const unsigned short* __restrict__ ue_bf,
    const int* __restrict__ off, const int* __restrict__ eid,
    const unsigned short* __restrict__ W0t, const float* __restrict__ b0,
    const unsigned short* __restrict__ W1t, const float* __restrict__ b1,
    const unsigned short* __restrict__ W2t, const float* __restrict__ b2,
    const float* __restrict__ g, const float* __restrict__ bt) {
  __shared__ __align__(16) unsigned short Ws[128 * WS_STRIDE];
  __shared__ __align__(16) unsigned short Ab[64 * AB_STRIDE];
  __shared__ __align__(16) unsigned short Ag[64 * AB_STRIDE];
  int tid = threadIdx.x;
  int w = tid >> 6, lane = tid & 63;
  int l4 = lane >> 4, l16 = lane & 15;
  int wrow = (w >> 1) * 32, wcol = (w & 1) * 64;
  int n0 = blockIdx.x * 64;
  // ---- phase A: agg rows into Ag (fp32 accum, CSR order) ----
  {
    int r = tid >> 2;
    int cseg = (tid & 3) * 32;
    int n = n0 + r;
    float a[32];
#pragma unroll
    for (int q = 0; q < 32; ++q) a[q] = 0.f;
    if (n < NN) {
      int p0 = off[n], p1 = off[n + 1];
      for (int p = p0; p < p1; ++p) {
        const unsigned short* row = ue_bf + (size_t)eid[p] * L + cseg;
#pragma unroll
        for (int q = 0; q < 4; ++q) {
          uint4 v = *(const uint4*)(row + q * 8);
          a[q * 8 + 0] += __builtin_bit_cast(float, v.x << 16);
          a[q * 8 + 1] += __builtin_bit_cast(float, v.x & 0xffff0000u);
          a[q * 8 + 2] += __builtin_bit_cast(float, v.y << 16);
          a[q * 8 + 3] += __builtin_bit_cast(float, v.y & 0xffff0000u);
          a[q * 8 + 4] += __builtin_bit_cast(float, v.z << 16);
          a[q * 8 + 5] += __builtin_bit_cast(float, v.z & 0xffff0000u);
          a[q * 8 + 6] += __builtin_bit_cast(float, v.w << 16);
          a[q * 8 + 7] += __builtin_bit_cast(float, v.w & 0xffff0000u);
        }
      }
    }
#pragma unroll
    for (int q = 0; q < 16; ++q) {
      unsigned o = (unsigned)f2bf(a[2 * q]) | ((unsigned)f2bf(a[2 * q + 1]) << 16);
      *(unsigned*)&Ag[r * AB_STRIDE + cseg + 2 * q] = o;
    }
  }
  stage_W(Ws, W0t, 256, 0, tid);
  f32x4 acc[2][4];
  init_acc(acc, b0, wcol, l16);
  __syncthreads();
  {
    const unsigned short* ap[2];
#pragma unroll
    for (int i = 0; i < 2; ++i)
      ap[i] = hx_bf + (size_t)min(n0 + wrow + i * 16 + l16, NN - 1) * L;
    layer_gbf(ap[0], ap[1], Ws, acc, wcol, l4, l16);
  }
  __syncthreads();
  stage_W(Ws, W0t, 256, 1, tid);
  __syncthreads();
  layer_lds(Ag, Ws, acc, wrow, wcol, l4, l16);
  __syncthreads();
  relu_to_Ab(Ab, acc, wrow, wcol, l4, l16);
  stage_W(Ws, W1t, 128, 0, tid);
  init_acc(acc, b1, wcol, l16);
  __syncthreads();
  layer_lds(Ab, Ws, acc, wrow, wcol, l4, l16);
  __syncthreads();
  relu_to_Ab(Ab, acc, wrow, wcol, l4, l16);
  stage_W(Ws, W2t, 128, 0, tid);
  init_acc(acc, b2, wcol, l16);
  __syncthreads();
  layer_lds(Ab, Ws, acc, wrow, wcol, l4, l16);
  float ps[2][4], ps2[2][4];
  ln_partials(acc, ps, ps2);
  __syncthreads();
  float* red = (float*)Ab;
  if (l16 == 0) {
#pragma unroll
    for (int i = 0; i < 2; ++i)
#pragma unroll
      for (int r = 0; r < 4; ++r) {
        int row = wrow + i * 16 + l4 * 4 + r;
        red[(w & 1) * 128 + row * 2 + 0] = ps[i][r];
        red[(w & 1) * 128 + row * 2 + 1] = ps2[i][r];
      }
  }
  __syncthreads();
  float gv[4], btv[4];
#pragma unroll
  for (int j = 0; j < 4; ++j) {
    int col = wcol + j * 16 + l16;
    gv[j] = g[col]; btv[j] = bt[col];
  }
#pragma unroll
  for (int i = 0; i < 2; ++i)
#pragma unroll
    for (int r = 0; r < 4; ++r) {
      int row = wrow + i * 16 + l4 * 4 + r;
      float s  = red[row * 2]     + red[128 + row * 2];
      float s2 = red[row * 2 + 1] + red[128 + row * 2 + 1];
      float m = s * (1.f / 128.f);
      float inv = rsqrtf(s2 * (1.f / 128.f) - m * m + 1e-5f);
      int n = n0 + row;
      if (n < NN) {
#pragma unroll
        for (int j = 0; j < 4; ++j) {
          int col = wcol + j * 16 + l16;
          float un = (acc[i][j][r] - m) * inv * gv[j] + btv[j];
          float nv = hx[(size_t)n * L + col] + un;
          hx[(size_t)n * L + col] = nv;
          hx_bf[(size_t)n * L + col] = f2bf(nv);
        }
      }
    }
}

// ================= edge encoder (R9) =================

__global__ __launch_bounds__(256) void enc_edge_mfma(
    const float* __restrict__ ea,
    const float* __restrict__ W0, const float* __restrict__ b0,
    const unsigned short* __restrict__ W1t, const float* __restrict__ b1,
    const unsigned short* __restrict__ W2t, const float* __restrict__ b2,
    const float* __restrict__ g, const float* __restrict__ bt,
    unsigned short* __restrict__ he_bf) {
  __shared__ __align__(16) unsigned short Ws[128 * WS_STRIDE];
  __shared__ __align__(16) unsigned short Ab[64 * AB_STRIDE];
  int tid = threadIdx.x;
  int w = tid >> 6, lane = tid & 63;
  int l4 = lane >> 4, l16 = lane & 15;
  int wrow = (w >> 1) * 32, wcol = (w & 1) * 64;
  int e0 = blockIdx.x * 64;
  {
    int row = tid >> 2, cbase = (tid & 3) * 32;
    int e = min(e0 + row, NE - 1);
    float4 eav = *(const float4*)&ea[(size_t)e * 4];
#pragma unroll
    for (int c = 0; c < 32; ++c) {
      int col = cbase + c;
      float sum = b0[col] + eav.x * W0[col] + eav.y * W0[128 + col] +
                  eav.z * W0[256 + col] + eav.w * W0[384 + col];
      Ab[row * AB_STRIDE + col] = f2bf(fmaxf(sum, 0.f));
    }
  }
  stage_W(Ws, W1t, 128, 0, tid);
  f32x4 acc[2][4];
  init_acc(acc, b1, wcol, l16);
  __syncthreads();
  layer_lds(Ab, Ws, acc, wrow, wcol, l4, l16);
  __syncthreads();
  relu_to_Ab(Ab, acc, wrow, wcol, l4, l16);
  stage_W(Ws, W2t, 128, 0, tid);
  init_acc(acc, b2, wcol, l16);
  __syncthreads();
  layer_lds(Ab, Ws, acc, wrow, wcol, l4, l16);
  float ps[2][4], ps2[2][4];
  ln_partials(acc, ps, ps2);
  __syncthreads();
  float* red = (float*)Ws;
  if (l16 == 0) {
#pragma unroll
    for (int i = 0; i < 2; ++i)
#pragma unroll
      for (int r = 0; r < 4; ++r) {
        int row = wrow + i * 16 + l4 * 4 + r;
        red[(w & 1) * 128 + row * 2 + 0] = ps[i][r];
        red[(w & 1) * 128 + row * 2 + 1] = ps2[i][r];
      }
  }
  __syncthreads();
  float gv[4], btv[4];
#pragma unroll
  for (int j = 0; j < 4; ++j) {
    int col = wcol + j * 16 + l16;
    gv[j] = g[col]; btv[j] = bt[col];
  }
#pragma unroll
  for (int i = 0; i < 2; ++i)
#pragma unroll
    for (int r = 0; r < 4; ++r) {
      int row = wrow + i * 16 + l4 * 4 + r;
      float s  = red[row * 2]     + red[128 + row * 2];
      float s2 = red[row * 2 + 1] + red[128 + row * 2 + 1];
      float m = s * (1.f / 128.f);
      float inv = rsqrtf(s2 * (1.f / 128.f) - m * m + 1e-5f);
      int e = e0 + row;
      if (e < NE) {
#pragma unroll
        for (int j = 0; j < 4; ++j) {
          int col = wcol + j * 16 + l16;
          he_bf[(size_t)e * L + col] = f2bf((acc[i][j][r] - m) * inv * gv[j] + btv[j]);
        }
      }
    }
}

// ================= weight prep =================

__global__ __launch_bounds__(256) void wprep_kernel(
    const float* __restrict__ W0, const float* __restrict__ W1, const float* __restrict__ W2,
    unsigned short* __restrict__ out, int K0, int steps) {
  int per_step = 128 * (K0 + 256);
  int idx = blockIdx.x * 256 + threadIdx.x;
  if (idx >= steps * per_step) return;
  int s = idx / per_step, r = idx - s * per_step;
  float v;
  if (r < 128 * K0) {
    int n = r / K0, k = r - n * K0;
    v = W0[(size_t)s * K0 * 128 + (size_t)k * 128 + n];
  } else {
    r -= 128 * K0;
    const float* W = (r < 16384) ? W1 : W2;
    r &= 16383;
    int n = r >> 7, k = r & 127;
    v = W[(size_t)s * 16384 + k * 128 + n];
  }
  out[idx] = f2bf(v);
}

__global__ __launch_bounds__(256) void tprep_kernel(
    const float* __restrict__ W1, const float* __restrict__ W2, unsigned short* __restrict__ out) {
  int idx = blockIdx.x * 256 + threadIdx.x;   // < 32768
  const float* W = (idx < 16384) ? W1 : W2;
  int r = idx & 16383;
  int n = r >> 7, k = r & 127;
  out[idx] = f2bf(W[k * 128 + n]);
}

// ================= fp32 helpers (encoder-node / decoder) =================

__device__ __forceinline__ void load_B(float* __restrict__ Bs, const float* __restrict__ W,
                                       int K, int k0, int tid) {
#pragma unroll
  for (int p = 0; p < 16; ++p) {
    int idx = tid + p * 256;
    int kk = idx >> 7;
    int c = idx & 127;
    float v = 0.f;
    if (k0 + kk < K) v = W[(size_t)(k0 + kk) * L + c];
    Bs[c * BP + kk] = v;
  }
}

__device__ __forceinline__ void fma32(const float* __restrict__ As, const float* __restrict__ Bs,
                                      float acc[4][8], int ty, int tx, int koff) {
#pragma unroll
  for (int kk = 0; kk < 32; kk += 4) {
    float4 a[4];
    float4 b[8];
#pragma unroll
    for (int i = 0; i < 4; ++i)
      a[i] = *(const float4*)&As[(ty + 16 * i) * AP + koff + kk];
#pragma unroll
    for (int j = 0; j < 8; ++j)
      b[j] = *(const float4*)&Bs[(tx + 16 * j) * BP + kk];
#pragma unroll
    for (int i = 0; i < 4; ++i)
#pragma unroll
      for (int j = 0; j < 8; ++j) {
        acc[i][j] = fmaf(a[i].x, b[j].x, acc[i][j]);
        acc[i][j] = fmaf(a[i].y, b[j].y, acc[i][j]);
        acc[i][j] = fmaf(a[i].z, b[j].z, acc[i][j]);
        acc[i][j] = fmaf(a[i].w, b[j].w, acc[i][j]);
      }
  }
}

__device__ __forceinline__ void init_bias(float acc[4][8], const float* __restrict__ b, int tx) {
#pragma unroll
  for (int j = 0; j < 8; ++j) {
    float bv = b[tx + 16 * j];
#pragma unroll
    for (int i = 0; i < 4; ++i) acc[i][j] = bv;
  }
}

__device__ __forceinline__ void store_relu(float* __restrict__ As, float acc[4][8], int ty, int tx) {
#pragma unroll
  for (int i = 0; i < 4; ++i)
#pragma unroll
    for (int j = 0; j < 8; ++j)
      As[(ty + 16 * i) * AP + tx + 16 * j] = fmaxf(acc[i][j], 0.f);
}

__device__ __forceinline__ void layer_As(const float* __restrict__ As, float* __restrict__ Bs,
                                         const float* __restrict__ W, const float* __restrict__ bias,
                                         int K, float acc[4][8], int tid, int ty, int tx) {
  init_bias(acc, bias, tx);
  int nc = (K + 31) >> 5;
  for (int bc = 0; bc < nc; ++bc) {
    __syncthreads();
    load_B(Bs, W, K, bc * 32, tid);
    __syncthreads();
    fma32(As, Bs, acc, ty, tx, bc * 32);
  }
}

__device__ __forceinline__ void fillA_gather(float* __restrict__ As, const float* __restrict__ base,
                                             const int* __restrict__ ridx, int tid) {
#pragma unroll
  for (int p = 0; p < 8; ++p) {
    int idx = tid + p * 256;
    int r = idx >> 5;
    int c4 = idx & 31;
    float4 v = *(const float4*)&base[(size_t)ridx[r] * L + c4 * 4];
    *(float4*)&As[r * AP + c4 * 4] = v;
  }
}

__device__ __forceinline__ void lnorm(float acc[4][8], const float* __restrict__ g,
                                      const float* __restrict__ bt, int tx) {
  float gv[8], bv[8];
#pragma unroll
  for (int j = 0; j < 8; ++j) { gv[j] = g[tx + 16 * j]; bv[j] = bt[tx + 16 * j]; }
#pragma unroll
  for (int i = 0; i < 4; ++i) {
    float s = 0.f, s2 = 0.f;
#pragma unroll
    for (int j = 0; j < 8; ++j) { s += acc[i][j]; s2 += acc[i][j] * acc[i][j]; }
#pragma unroll
    for (int off = 1; off < 16; off <<= 1) {
      s  += __shfl_xor(s, off, 64);
      s2 += __shfl_xor(s2, off, 64);
    }
    float m = s * (1.f / 128.f);
    float var = s2 * (1.f / 128.f) - m * m;
    float inv = rsqrtf(var + 1e-5f);
#pragma unroll
    for (int j = 0; j < 8; ++j) acc[i][j] = (acc[i][j] - m) * inv * gv[j] + bv[j];
  }
}

__global__ __launch_bounds__(256) void enc_node_kernel(
    const float* __restrict__ x,
    const float* __restrict__ W0, const float* __restrict__ b0,
    const float* __restrict__ W1, const float* __restrict__ b1,
    const float* __restrict__ W2, const float* __restrict__ b2,
    const float* __restrict__ g, const float* __restrict__ bt,
    float* __restrict__ hx, unsigned short* __restrict__ hx_bf) {
  __shared__ float As[64 * AP];
  __shared__ float Bs[128 * BP];
  int tid = threadIdx.x, ty = tid >> 4, tx = tid & 15;
  int n0 = blockIdx.x * 64;
#pragma unroll
  for (int p = 0; p < 8; ++p) {
    int idx = tid + p * 256;
    int r = idx >> 5, c = idx & 31;
    int n = min(n0 + r, NN - 1);
    As[r * AP + c] = (c < NODE_F) ? x[(size_t)n * NODE_F + c] : 0.f;
  }
  float acc[4][8];
  init_bias(acc, b0, tx);
  __syncthreads();
  load_B(Bs, W0, NODE_F, 0, tid);
  __syncthreads();
  fma32(As, Bs, acc, ty, tx, 0);

  __syncthreads(); store_relu(As, acc, ty, tx);
  layer_As(As, Bs, W1, b1, L, acc, tid, ty, tx);
  __syncthreads(); store_relu(As, acc, ty, tx);
  layer_As(As, Bs, W2, b2, L, acc, tid, ty, tx);
  lnorm(acc, g, bt, tx);
#pragma unroll
  for (int i = 0; i < 4; ++i) {
    int n = n0 + ty + 16 * i;
    if (n < NN)
#pragma unroll
      for (int j = 0; j < 8; ++j) {
        float v = acc[i][j];
        hx[(size_t)n * L + tx + 16 * j] = v;
        hx_bf[(size_t)n * L + tx + 16 * j] = f2bf(v);
      }
  }
}

__global__ __launch_bounds__(256) void dec_kernel(
    const float* __restrict__ hx,
    const float* __restrict__ W0, const float* __restrict__ b0,
    const float* __restrict__ W1, const float* __restrict__ b1,
    const float* __restrict__ W2, const float* __restrict__ b2,
    float* __restrict__ out) {
  __shared__ float As[64 * AP];
  __shared__ float Bs[128 * BP];
  __shared__ int nidx[64];
  int tid = threadIdx.x, ty = tid >> 4, tx = tid & 15;
  int n0 = blockIdx.x * 64;
  if (tid < 64) nidx[tid] = min(n0 + tid, NN - 1);
  __syncthreads();
  fillA_gather(As, hx, nidx, tid);
  float acc[4][8];
  layer_As(As, Bs, W0, b0, L, acc, tid, ty, tx);
  __syncthreads(); store_relu(As, acc, ty, tx);
  layer_As(As, Bs, W1, b1, L, acc, tid, ty, tx);
  __syncthreads(); store_relu(As, acc, ty, tx);
  __syncthreads();
  if (tid < 192) {
    int r = tid / 3, o = tid - (tid / 3) * 3;
    int n = n0 + r;
    if (n < NN) {
      float s = b2[o];
#pragma unroll 8
      for (int k = 0; k < L; ++k) s = fmaf(As[r * AP + k], W2[k * 3 + o], s);
      out[(size_t)n * 3 + o] = s;
    }
  }
}

// ================= launch =================

extern "C" void kernel_launch(void* const* d_in, const int* in_sizes, int n_in,
                              void* d_out, int out_size, void* d_ws, size_t ws_size,
                              hipStream_t stream) {
  (void)in_sizes; (void)n_in; (void)out_size; (void)ws_size;
  const float* x    = (const float*)d_in[0];
  const float* ea   = (const float*)d_in[1];
  const int*   ei   = (const int*)d_in[2];
  const float* enW0 = (const float*)d_in[3];  const float* enb0 = (const float*)d_in[4];
  const float* enW1 = (const float*)d_in[5];  const float* enb1 = (const float*)d_in[6];
  const float* enW2 = (const float*)d_in[7];  const float* enb2 = (const float*)d_in[8];
  const float* eng  = (const float*)d_in[9];  const float* enbt = (const float*)d_in[10];
  const float* eeW0 = (const float*)d_in[11]; const float* eeb0 = (const float*)d_in[12];
  const float* eeW1 = (const float*)d_in[13]; const float* eeb1 = (const float*)d_in[14];
  const float* eeW2 = (const float*)d_in[15]; const float* eeb2 = (const float*)d_in[16];
  const float* eeg  = (const float*)d_in[17]; const float* eebt = (const float*)d_in[18];
  const float* peW0 = (const float*)d_in[19]; const float* peb0 = (const float*)d_in[20];
  const float* peW1 = (const float*)d_in[21]; const float* peb1 = (const float*)d_in[22];
  const float* peW2 = (const float*)d_in[23]; const float* peb2 = (const float*)d_in[24];
  const float* peg  = (const float*)d_in[25]; const float* pebt = (const float*)d_in[26];
  const float* pnW0 = (const float*)d_in[27]; const float* pnb0 = (const float*)d_in[28];
  const float* pnW1 = (const float*)d_in[29]; const float* pnb1 = (const float*)d_in[30];
  const float* pnW2 = (const float*)d_in[31]; const float* pnb2 = (const float*)d_in[32];
  const float* png  = (const float*)d_in[33]; const float* pnbt = (const float*)d_in[34];
  const float* dW0  = (const float*)d_in[35]; const float* db0  = (const float*)d_in[36];
  const float* dW1  = (const float*)d_in[37]; const float* db1  = (const float*)d_in[38];
  const float* dW2  = (const float*)d_in[39]; const float* db2  = (const float*)d_in[40];

  const size_t F_HX = (size_t)NN * L, F_HE = (size_t)NE * L;
  const size_t W_PE = 819200, W_PN = 655360, W_EE = 32768;

  float* hx = (float*)d_ws;                              // NN*L fp32
  unsigned short* he_bf  = (unsigned short*)(hx + F_HX); // NE*L bf16
  unsigned short* ue_bf  = he_bf + F_HE;                 // NE*L bf16
  unsigned short* hx_bf  = ue_bf + F_HE;                 // NN*L bf16
  unsigned short* wt_pe  = hx_bf + F_HX;
  unsigned short* wt_pn  = wt_pe + W_PE;
  unsigned short* wt_ee  = wt_pn + W_PN;
  int* cnt = (int*)(wt_ee + W_EE);
  int* off = cnt + NN;
  int* cur = off + NN + 1;
  int* eid = cur + NN;

  dim3 blk(256);
  int grid_n = (NN + 63) / 64;   // 157
  int grid_e = (NE + 63) / 64;   // 1563

  wprep_kernel<<<(10 * 81920 + 255) / 256, blk, 0, stream>>>(peW0, peW1, peW2, wt_pe, 384, 10);
  wprep_kernel<<<(10 * 65536 + 255) / 256, blk, 0, stream>>>(pnW0, pnW1, pnW2, wt_pn, 256, 10);
  tprep_kernel<<<128, blk, 0, stream>>>(eeW1, eeW2, wt_ee);

  hipMemsetAsync(cnt, 0, (size_t)NN * 4, stream);
  deg_kernel<<<(NE + 255) / 256, blk, 0, stream>>>(ei, cnt);
  scan_kernel<<<1, blk, 0, stream>>>(cnt, off, cur);
  scatter_kernel<<<(NE + 255) / 256, blk, 0, stream>>>(ei, cur, eid);

  enc_node_kernel<<<grid_n, blk, 0, stream>>>(x, enW0, enb0, enW1, enb1, enW2, enb2, eng, enbt, hx, hx_bf);
  enc_edge_mfma<<<grid_e, blk, 0, stream>>>(ea, eeW0, eeb0, wt_ee, eeb1, wt_ee + 16384, eeb2, eeg, eebt, he_bf);

  for (int s = 0; s < STEPS; ++s) {
    const unsigned short* pe = wt_pe + (size_t)s * 81920;
    const unsigned short* pn = wt_pn + (size_t)s * 65536;
    edge_step_mfma<<<grid_e, blk, 0, stream>>>(
        hx_bf, he_bf, ue_bf, ei,
        pe,                 peb0 + (size_t)s * L,
        pe + 49152,         peb1 + (size_t)s * L,
        pe + 49152 + 16384, peb2 + (size_t)s * L,
        peg + (size_t)s * L, pebt + (size_t)s * L);
    node_step_mfma<<<grid_n, blk, 0, stream>>>(
        hx, hx_bf, ue_bf, off, eid,
        pn,                 pnb0 + (size_t)s * L,
        pn + 32768,         pnb1 + (size_t)s * L,
        pn + 32768 + 16384, pnb2 + (size_t)s * L,
        png + (size_t)s * L, pnbt + (size_t)s * L);
  }

  dec_kernel<<<grid_n, blk, 0, stream>>>(hx, dW0, db0, dW1, db1, dW2, db2, (float*)d_out);
}

// Round 13
// 959.777 us; speedup vs baseline: 1.4646x; 1.4646x over previous
//
#include <hip/hip_runtime.h>

// EncodeProcessDecode (GNS): N=10000 nodes, E=100000 edges, S=10 steps, L=H=128.
// Round 13: restore R9 (948us proven best; R10/R11/R12 perturbations all
// regressed -> R9 structure is a sharp local optimum at 3 blocks/CU).
// Only change vs R9: s_setprio(1) around MFMA clusters (T5 — blocks at
// different phases per CU, matching the attn-case win condition).

#define NN 10000
#define NE 100000
#define STEPS 10
#define NODE_F 30
#define EDGE_F 4
#define L 128
#define AP 132   // fp32 helper LDS stride (encoder-node / decoder)
#define BP 36

#define WS_STRIDE 136   // bf16 elems per LDS row: 128 + 8 pad
#define AB_STRIDE 136

typedef __bf16 bf16x8 __attribute__((ext_vector_type(8)));
typedef float f32x4 __attribute__((ext_vector_type(4)));

__device__ __forceinline__ unsigned short f2bf(float f) {
  __bf16 b = (__bf16)f;
  return __builtin_bit_cast(unsigned short, b);
}
__device__ __forceinline__ float bf2f(unsigned short u) {
  return __builtin_bit_cast(float, (unsigned)u << 16);
}

// ================= staging =================

__device__ __forceinline__ void stage_W(unsigned short* __restrict__ Ws,
                                        const unsigned short* __restrict__ Wt,
                                        int K, int sec, int tid) {
#pragma unroll
  for (int p = 0; p < 8; ++p) {
    int u = tid + p * 256;
    int n = u >> 4, kk = u & 15;
    uint4 v = *(const uint4*)(Wt + (size_t)n * K + sec * 128 + kk * 8);
    *(uint4*)&Ws[n * WS_STRIDE + kk * 8] = v;
  }
}

// ================= MFMA helpers (2x4: wave tile 32x64) =================

__device__ __forceinline__ void init_acc(f32x4 acc[2][4], const float* __restrict__ b,
                                         int wcol, int l16) {
#pragma unroll
  for (int j = 0; j < 4; ++j) {
    float bv = b[wcol + j * 16 + l16];
#pragma unroll
    for (int i = 0; i < 2; ++i) acc[i][j] = f32x4{bv, bv, bv, bv};
  }
}

__device__ __forceinline__ void layer_gbf(const unsigned short* __restrict__ ap0,
                                          const unsigned short* __restrict__ ap1,
                                          const unsigned short* __restrict__ Ws,
                                          f32x4 acc[2][4], int wcol, int l4, int l16) {
  __builtin_amdgcn_s_setprio(1);
#pragma unroll
  for (int kk = 0; kk < 4; ++kk) {
    bf16x8 af[2];
    af[0] = *(const bf16x8*)(ap0 + kk * 32 + l4 * 8);
    af[1] = *(const bf16x8*)(ap1 + kk * 32 + l4 * 8);
#pragma unroll
    for (int j = 0; j < 4; ++j) {
      bf16x8 bv = *(const bf16x8*)&Ws[(wcol + j * 16 + l16) * WS_STRIDE + kk * 32 + l4 * 8];
#pragma unroll
      for (int i = 0; i < 2; ++i)
        acc[i][j] = __builtin_amdgcn_mfma_f32_16x16x32_bf16(af[i], bv, acc[i][j], 0, 0, 0);
    }
  }
  __builtin_amdgcn_s_setprio(0);
}

__device__ __forceinline__ void layer_lds(const unsigned short* __restrict__ Ab,
                                          const unsigned short* __restrict__ Ws,
                                          f32x4 acc[2][4], int wrow, int wcol, int l4, int l16) {
  __builtin_amdgcn_s_setprio(1);
#pragma unroll
  for (int kk = 0; kk < 4; ++kk) {
    bf16x8 af[2];
#pragma unroll
    for (int i = 0; i < 2; ++i)
      af[i] = *(const bf16x8*)&Ab[(wrow + i * 16 + l16) * AB_STRIDE + kk * 32 + l4 * 8];
#pragma unroll
    for (int j = 0; j < 4; ++j) {
      bf16x8 bv = *(const bf16x8*)&Ws[(wcol + j * 16 + l16) * WS_STRIDE + kk * 32 + l4 * 8];
#pragma unroll
      for (int i = 0; i < 2; ++i)
        acc[i][j] = __builtin_amdgcn_mfma_f32_16x16x32_bf16(af[i], bv, acc[i][j], 0, 0, 0);
    }
  }
  __builtin_amdgcn_s_setprio(0);
}

__device__ __forceinline__ void relu_to_Ab(unsigned short* __restrict__ Ab, f32x4 acc[2][4],
                                           int wrow, int wcol, int l4, int l16) {
#pragma unroll
  for (int i = 0; i < 2; ++i)
#pragma unroll
    for (int j = 0; j < 4; ++j)
#pragma unroll
      for (int r = 0; r < 4; ++r) {
        int row = wrow + i * 16 + l4 * 4 + r;
        int col = wcol + j * 16 + l16;
        Ab[row * AB_STRIDE + col] = f2bf(fmaxf(acc[i][j][r], 0.f));
      }
}

__device__ __forceinline__ void ln_partials(const f32x4 acc[2][4], float ps[2][4], float ps2[2][4]) {
#pragma unroll
  for (int i = 0; i < 2; ++i)
#pragma unroll
    for (int r = 0; r < 4; ++r) {
      float s = 0.f, s2 = 0.f;
#pragma unroll
      for (int j = 0; j < 4; ++j) { float v = acc[i][j][r]; s += v; s2 += v * v; }
#pragma unroll
      for (int off = 1; off < 16; off <<= 1) {
        s += __shfl_xor(s, off, 64);
        s2 += __shfl_xor(s2, off, 64);
      }
      ps[i][r] = s; ps2[i][r] = s2;
    }
}

// ================= CSR prep =================

__global__ __launch_bounds__(256) void deg_kernel(const int* __restrict__ ei, int* __restrict__ cnt) {
  int e = blockIdx.x * 256 + threadIdx.x;
  if (e < NE) atomicAdd(&cnt[ei[NE + e]], 1);
}

__global__ __launch_bounds__(256) void scan_kernel(const int* __restrict__ cnt,
                                                   int* __restrict__ off, int* __restrict__ cur) {
  __shared__ int sums[256];
  int t = threadIdx.x;
  int base = t * 40;   // 256*40 = 10240 >= NN
  int local = 0;
  for (int i = 0; i < 40; ++i) { int n = base + i; if (n < NN) local += cnt[n]; }
  sums[t] = local;
  __syncthreads();
  int val = local;
  for (int d = 1; d < 256; d <<= 1) {
    int add = (t >= d) ? sums[t - d] : 0;
    __syncthreads();
    sums[t] += add;
    __syncthreads();
  }
  int run = sums[t] - val;
  for (int i = 0; i < 40; ++i) {
    int n = base + i;
    if (n < NN) { off[n] = run; cur[n] = run; run += cnt[n]; }
  }
  if (t == 255) off[NN] = sums[255];
}

__global__ __launch_bounds__(256) void scatter_kernel(const int* __restrict__ ei,
                                                      int* __restrict__ cur, int* __restrict__ eid) {
  int e = blockIdx.x * 256 + threadIdx.x;
  if (e < NE) { int p = atomicAdd(&cur[ei[NE + e]], 1); eid[p] = e; }
}

// ================= edge step (R9 structure) =================

__global__ __launch_bounds__(256) void edge_step_mfma(
    const unsigned short* __restrict__ hx_bf, unsigned short* __restrict__ he_bf,
    unsigned short* __restrict__ ue_bf,
    const int* __restrict__ ei,
    const unsigned short* __restrict__ W0t, const float* __restrict__ b0,
    const unsigned short* __restrict__ W1t, const float* __restrict__ b1,
    const unsigned short* __restrict__ W2t, const float* __restrict__ b2,
    const float* __restrict__ g, const float* __restrict__ bt) {
  __shared__ __align__(16) unsigned short Ws[128 * WS_STRIDE];
  __shared__ __align__(16) unsigned short Ab[64 * AB_STRIDE];
  __shared__ int sidx[64], didx[64];
  int tid = threadIdx.x;
  int w = tid >> 6, lane = tid & 63;
  int l4 = lane >> 4, l16 = lane & 15;
  int wrow = (w >> 1) * 32, wcol = (w & 1) * 64;
  int e0 = blockIdx.x * 64;
  if (tid < 64) {
    int e = min(e0 + tid, NE - 1);
    sidx[tid] = ei[e];
    didx[tid] = ei[NE + e];
  }
  f32x4 acc[2][4];
  init_acc(acc, b0, wcol, l16);
  __syncthreads();
  // ---- layer0: K=384 = [hx[src] | hx[dst] | he], A direct bf16 ----
  for (int sec = 0; sec < 3; ++sec) {
    stage_W(Ws, W0t, 384, sec, tid);
    const unsigned short* ap[2];
#pragma unroll
    for (int i = 0; i < 2; ++i) {
      int r = wrow + i * 16 + l16;
      if (sec == 0)      ap[i] = hx_bf + (size_t)sidx[r] * L;
      else if (sec == 1) ap[i] = hx_bf + (size_t)didx[r] * L;
      else               ap[i] = he_bf + (size_t)min(e0 + r, NE - 1) * L;
    }
    __syncthreads();
    layer_gbf(ap[0], ap[1], Ws, acc, wcol, l4, l16);
    __syncthreads();
  }
  // ---- layer1 ----
  relu_to_Ab(Ab, acc, wrow, wcol, l4, l16);
  stage_W(Ws, W1t, 128, 0, tid);
  init_acc(acc, b1, wcol, l16);
  __syncthreads();
  layer_lds(Ab, Ws, acc, wrow, wcol, l4, l16);
  __syncthreads();
  // ---- layer2 (no relu after) ----
  relu_to_Ab(Ab, acc, wrow, wcol, l4, l16);
  stage_W(Ws, W2t, 128, 0, tid);
  init_acc(acc, b2, wcol, l16);
  __syncthreads();
  layer_lds(Ab, Ws, acc, wrow, wcol, l4, l16);
  // ---- LayerNorm ----
  float ps[2][4], ps2[2][4];
  ln_partials(acc, ps, ps2);
  __syncthreads();                       // Ab reads done; red overlays Ab
  float* red = (float*)Ab;               // [2 halves][64 rows][2]
  if (l16 == 0) {
#pragma unroll
    for (int i = 0; i < 2; ++i)
#pragma unroll
      for (int r = 0; r < 4; ++r) {
        int row = wrow + i * 16 + l4 * 4 + r;
        red[(w & 1) * 128 + row * 2 + 0] = ps[i][r];
        red[(w & 1) * 128 + row * 2 + 1] = ps2[i][r];
      }
  }
  __syncthreads();
  float gv[4], btv[4];
#pragma unroll
  for (int j = 0; j < 4; ++j) {
    int col = wcol + j * 16 + l16;
    gv[j] = g[col]; btv[j] = bt[col];
  }
#pragma unroll
  for (int i = 0; i < 2; ++i)
#pragma unroll
    for (int r = 0; r < 4; ++r) {
      int row = wrow + i * 16 + l4 * 4 + r;
      float s  = red[row * 2]     + red[128 + row * 2];
      float s2 = red[row * 2 + 1] + red[128 + row * 2 + 1];
      float m = s * (1.f / 128.f);
      float inv = rsqrtf(s2 * (1.f / 128.f) - m * m + 1e-5f);
      int e = e0 + row;
      if (e < NE) {
        size_t hoff = (size_t)e * L;
#pragma unroll
        for (int j = 0; j < 4; ++j) {
          int col = wcol + j * 16 + l16;
          float u = (acc[i][j][r] - m) * inv * gv[j] + btv[j];
          unsigned short old = he_bf[hoff + col];
          he_bf[hoff + col] = f2bf(bf2f(old) + u);
          ue_bf[hoff + col] = f2bf(u);
        }
      }
    }
}

// ================= node step: fused CSR aggregation (R9) =================

__global__ __launch_bounds__(256) void node_step_mfma(
    float* __restrict__ hx, unsigned short* __restrict__ hx_bf,
    const unsigned short* __restrict__ ue_bf,
    const int* __restrict__ off, const int* __restrict__ eid,
    const unsigned short* __restrict__ W0t, const float* __restrict__ b0,
    const unsigned short* __restrict__ W1t, const float* __restrict__ b1,
    const unsigned short* __restrict__ W2t, const float* __restrict__ b2,
    const float* __restrict__ g, const float* __restrict__ bt) {
  __shared__ __align__(16) unsigned short Ws[128 * WS_STRIDE];
  __shared__ __align__(16) unsigned short Ab[64 * AB_STRIDE];
  __shared__ __align__(16) unsigned short Ag[64 * AB_STRIDE];
  int tid = threadIdx.x;
  int w = tid >> 6, lane = tid & 63;
  int l4 = lane >> 4, l16 = lane & 15;
  int wrow = (w >> 1) * 32, wcol = (w & 1) * 64;
  int n0 = blockIdx.x * 64;
  // ---- phase A: agg rows into Ag (fp32 accum, CSR order) ----
  {
    int r = tid >> 2;
    int cseg = (tid & 3) * 32;
    int n = n0 + r;
    float a[32];
#pragma unroll
    for (int q = 0; q < 32; ++q) a[q] = 0.f;
    if (n < NN) {
      int p0 = off[n], p1 = off[n + 1];
      for (int p = p0; p < p1; ++p) {
        const unsigned short* row = ue_bf + (size_t)eid[p] * L + cseg;
#pragma unroll
        for (int q = 0; q < 4; ++q) {
          uint4 v = *(const uint4*)(row + q * 8);
          a[q * 8 + 0] += __builtin_bit_cast(float, v.x << 16);
          a[q * 8 + 1] += __builtin_bit_cast(float, v.x & 0xffff0000u);
          a[q * 8 + 2] += __builtin_bit_cast(float, v.y << 16);
          a[q * 8 + 3] += __builtin_bit_cast(float, v.y & 0xffff0000u);
          a[q * 8 + 4] += __builtin_bit_cast(float, v.z << 16);
          a[q * 8 + 5] += __builtin_bit_cast(float, v.z & 0xffff0000u);
          a[q * 8 + 6] += __builtin_bit_cast(float, v.w << 16);
          a[q * 8 + 7] += __builtin_bit_cast(float, v.w & 0xffff0000u);
        }
      }
    }
#pragma unroll
    for (int q = 0; q < 16; ++q) {
      unsigned o = (unsigned)f2bf(a[2 * q]) | ((unsigned)f2bf(a[2 * q + 1]) << 16);
      *(unsigned*)&Ag[r * AB_STRIDE + cseg + 2 * q] = o;
    }
  }
  stage_W(Ws, W0t, 256, 0, tid);
  f32x4 acc[2][4];
  init_acc(acc, b0, wcol, l16);
  __syncthreads();
  {
    const unsigned short* ap[2];
#pragma unroll
    for (int i = 0; i < 2; ++i)
      ap[i] = hx_bf + (size_t)min(n0 + wrow + i * 16 + l16, NN - 1) * L;
    layer_gbf(ap[0], ap[1], Ws, acc, wcol, l4, l16);
  }
  __syncthreads();
  stage_W(Ws, W0t, 256, 1, tid);
  __syncthreads();
  layer_lds(Ag, Ws, acc, wrow, wcol, l4, l16);
  __syncthreads();
  relu_to_Ab(Ab, acc, wrow, wcol, l4, l16);
  stage_W(Ws, W1t, 128, 0, tid);
  init_acc(acc, b1, wcol, l16);
  __syncthreads();
  layer_lds(Ab, Ws, acc, wrow, wcol, l4, l16);
  __syncthreads();
  relu_to_Ab(Ab, acc, wrow, wcol, l4, l16);
  stage_W(Ws, W2t, 128, 0, tid);
  init_acc(acc, b2, wcol, l16);
  __syncthreads();
  layer_lds(Ab, Ws, acc, wrow, wcol, l4, l16);
  float ps[2][4], ps2[2][4];
  ln_partials(acc, ps, ps2);
  __syncthreads();
  float* red = (float*)Ab;
  if (l16 == 0) {
#pragma unroll
    for (int i = 0; i < 2; ++i)
#pragma unroll
      for (int r = 0; r < 4; ++r) {
        int row = wrow + i * 16 + l4 * 4 + r;
        red[(w & 1) * 128 + row * 2 + 0] = ps[i][r];
        red[(w & 1) * 128 + row * 2 + 1] = ps2[i][r];
      }
  }
  __syncthreads();
  float gv[4], btv[4];
#pragma unroll
  for (int j = 0; j < 4; ++j) {
    int col = wcol + j * 16 + l16;
    gv[j] = g[col]; btv[j] = bt[col];
  }
#pragma unroll
  for (int i = 0; i < 2; ++i)
#pragma unroll
    for (int r = 0; r < 4; ++r) {
      int row = wrow + i * 16 + l4 * 4 + r;
      float s  = red[row * 2]     + red[128 + row * 2];
      float s2 = red[row * 2 + 1] + red[128 + row * 2 + 1];
      float m = s * (1.f / 128.f);
      float inv = rsqrtf(s2 * (1.f / 128.f) - m * m + 1e-5f);
      int n = n0 + row;
      if (n < NN) {
#pragma unroll
        for (int j = 0; j < 4; ++j) {
          int col = wcol + j * 16 + l16;
          float un = (acc[i][j][r] - m) * inv * gv[j] + btv[j];
          float nv = hx[(size_t)n * L + col] + un;
          hx[(size_t)n * L + col] = nv;
          hx_bf[(size_t)n * L + col] = f2bf(nv);
        }
      }
    }
}

// ================= edge encoder (R9) =================

__global__ __launch_bounds__(256) void enc_edge_mfma(
    const float* __restrict__ ea,
    const float* __restrict__ W0, const float* __restrict__ b0,
    const unsigned short* __restrict__ W1t, const float* __restrict__ b1,
    const unsigned short* __restrict__ W2t, const float* __restrict__ b2,
    const float* __restrict__ g, const float* __restrict__ bt,
    unsigned short* __restrict__ he_bf) {
  __shared__ __align__(16) unsigned short Ws[128 * WS_STRIDE];
  __shared__ __align__(16) unsigned short Ab[64 * AB_STRIDE];
  int tid = threadIdx.x;
  int w = tid >> 6, lane = tid & 63;
  int l4 = lane >> 4, l16 = lane & 15;
  int wrow = (w >> 1) * 32, wcol = (w & 1) * 64;
  int e0 = blockIdx.x * 64;
  {
    int row = tid >> 2, cbase = (tid & 3) * 32;
    int e = min(e0 + row, NE - 1);
    float4 eav = *(const float4*)&ea[(size_t)e * 4];
#pragma unroll
    for (int c = 0; c < 32; ++c) {
      int col = cbase + c;
      float sum = b0[col] + eav.x * W0[col] + eav.y * W0[128 + col] +
                  eav.z * W0[256 + col] + eav.w * W0[384 + col];
      Ab[row * AB_STRIDE + col] = f2bf(fmaxf(sum, 0.f));
    }
  }
  stage_W(Ws, W1t, 128, 0, tid);
  f32x4 acc[2][4];
  init_acc(acc, b1, wcol, l16);
  __syncthreads();
  layer_lds(Ab, Ws, acc, wrow, wcol, l4, l16);
  __syncthreads();
  relu_to_Ab(Ab, acc, wrow, wcol, l4, l16);
  stage_W(Ws, W2t, 128, 0, tid);
  init_acc(acc, b2, wcol, l16);
  __syncthreads();
  layer_lds(Ab, Ws, acc, wrow, wcol, l4, l16);
  float ps[2][4], ps2[2][4];
  ln_partials(acc, ps, ps2);
  __syncthreads();
  float* red = (float*)Ws;
  if (l16 == 0) {
#pragma unroll
    for (int i = 0; i < 2; ++i)
#pragma unroll
      for (int r = 0; r < 4; ++r) {
        int row = wrow + i * 16 + l4 * 4 + r;
        red[(w & 1) * 128 + row * 2 + 0] = ps[i][r];
        red[(w & 1) * 128 + row * 2 + 1] = ps2[i][r];
      }
  }
  __syncthreads();
  float gv[4], btv[4];
#pragma unroll
  for (int j = 0; j < 4; ++j) {
    int col = wcol + j * 16 + l16;
    gv[j] = g[col]; btv[j] = bt[col];
  }
#pragma unroll
  for (int i = 0; i < 2; ++i)
#pragma unroll
    for (int r = 0; r < 4; ++r) {
      int row = wrow + i * 16 + l4 * 4 + r;
      float s  = red[row * 2]     + red[128 + row * 2];
      float s2 = red[row * 2 + 1] + red[128 + row * 2 + 1];
      float m = s * (1.f / 128.f);
      float inv = rsqrtf(s2 * (1.f / 128.f) - m * m + 1e-5f);
      int e = e0 + row;
      if (e < NE) {
#pragma unroll
        for (int j = 0; j < 4; ++j) {
          int col = wcol + j * 16 + l16;
          he_bf[(size_t)e * L + col] = f2bf((acc[i][j][r] - m) * inv * gv[j] + btv[j]);
        }
      }
    }
}

// ================= weight prep =================

__global__ __launch_bounds__(256) void wprep_kernel(
    const float* __restrict__ W0, const float* __restrict__ W1, const float* __restrict__ W2,
    unsigned short* __restrict__ out, int K0, int steps) {
  int per_step = 128 * (K0 + 256);
  int idx = blockIdx.x * 256 + threadIdx.x;
  if (idx >= steps * per_step) return;
  int s = idx / per_step, r = idx - s * per_step;
  float v;
  if (r < 128 * K0) {
    int n = r / K0, k = r - n * K0;
    v = W0[(size_t)s * K0 * 128 + (size_t)k * 128 + n];
  } else {
    r -= 128 * K0;
    const float* W = (r < 16384) ? W1 : W2;
    r &= 16383;
    int n = r >> 7, k = r & 127;
    v = W[(size_t)s * 16384 + k * 128 + n];
  }
  out[idx] = f2bf(v);
}

__global__ __launch_bounds__(256) void tprep_kernel(
    const float* __restrict__ W1, const float* __restrict__ W2, unsigned short* __restrict__ out) {
  int idx = blockIdx.x * 256 + threadIdx.x;   // < 32768
  const float* W = (idx < 16384) ? W1 : W2;
  int r = idx & 16383;
  int n = r >> 7, k = r & 127;
  out[idx] = f2bf(W[k * 128 + n]);
}

// ================= fp32 helpers (encoder-node / decoder) =================

__device__ __forceinline__ void load_B(float* __restrict__ Bs, const float* __restrict__ W,
                                       int K, int k0, int tid) {
#pragma unroll
  for (int p = 0; p < 16; ++p) {
    int idx = tid + p * 256;
    int kk = idx >> 7;
    int c = idx & 127;
    float v = 0.f;
    if (k0 + kk < K) v = W[(size_t)(k0 + kk) * L + c];
    Bs[c * BP + kk] = v;
  }
}

__device__ __forceinline__ void fma32(const float* __restrict__ As, const float* __restrict__ Bs,
                                      float acc[4][8], int ty, int tx, int koff) {
#pragma unroll
  for (int kk = 0; kk < 32; kk += 4) {
    float4 a[4];
    float4 b[8];
#pragma unroll
    for (int i = 0; i < 4; ++i)
      a[i] = *(const float4*)&As[(ty + 16 * i) * AP + koff + kk];
#pragma unroll
    for (int j = 0; j < 8; ++j)
      b[j] = *(const float4*)&Bs[(tx + 16 * j) * BP + kk];
#pragma unroll
    for (int i = 0; i < 4; ++i)
#pragma unroll
      for (int j = 0; j < 8; ++j) {
        acc[i][j] = fmaf(a[i].x, b[j].x, acc[i][j]);
        acc[i][j] = fmaf(a[i].y, b[j].y, acc[i][j]);
        acc[i][j] = fmaf(a[i].z, b[j].z, acc[i][j]);
        acc[i][j] = fmaf(a[i].w, b[j].w, acc[i][j]);
      }
  }
}

__device__ __forceinline__ void init_bias(float acc[4][8], const float* __restrict__ b, int tx) {
#pragma unroll
  for (int j = 0; j < 8; ++j) {
    float bv = b[tx + 16 * j];
#pragma unroll
    for (int i = 0; i < 4; ++i) acc[i][j] = bv;
  }
}

__device__ __forceinline__ void store_relu(float* __restrict__ As, float acc[4][8], int ty, int tx) {
#pragma unroll
  for (int i = 0; i < 4; ++i)
#pragma unroll
    for (int j = 0; j < 8; ++j)
      As[(ty + 16 * i) * AP + tx + 16 * j] = fmaxf(acc[i][j], 0.f);
}

__device__ __forceinline__ void layer_As(const float* __restrict__ As, float* __restrict__ Bs,
                                         const float* __restrict__ W, const float* __restrict__ bias,
                                         int K, float acc[4][8], int tid, int ty, int tx) {
  init_bias(acc, bias, tx);
  int nc = (K + 31) >> 5;
  for (int bc = 0; bc < nc; ++bc) {
    __syncthreads();
    load_B(Bs, W, K, bc * 32, tid);
    __syncthreads();
    fma32(As, Bs, acc, ty, tx, bc * 32);
  }
}

__device__ __forceinline__ void fillA_gather(float* __restrict__ As, const float* __restrict__ base,
                                             const int* __restrict__ ridx, int tid) {
#pragma unroll
  for (int p = 0; p < 8; ++p) {
    int idx = tid + p * 256;
    int r = idx >> 5;
    int c4 = idx & 31;
    float4 v = *(const float4*)&base[(size_t)ridx[r] * L + c4 * 4];
    *(float4*)&As[r * AP + c4 * 4] = v;
  }
}

__device__ __forceinline__ void lnorm(float acc[4][8], const float* __restrict__ g,
                                      const float* __restrict__ bt, int tx) {
  float gv[8], bv[8];
#pragma unroll
  for (int j = 0; j < 8; ++j) { gv[j] = g[tx + 16 * j]; bv[j] = bt[tx + 16 * j]; }
#pragma unroll
  for (int i = 0; i < 4; ++i) {
    float s = 0.f, s2 = 0.f;
#pragma unroll
    for (int j = 0; j < 8; ++j) { s += acc[i][j]; s2 += acc[i][j] * acc[i][j]; }
#pragma unroll
    for (int off = 1; off < 16; off <<= 1) {
      s  += __shfl_xor(s, off, 64);
      s2 += __shfl_xor(s2, off, 64);
    }
    float m = s * (1.f / 128.f);
    float var = s2 * (1.f / 128.f) - m * m;
    float inv = rsqrtf(var + 1e-5f);
#pragma unroll
    for (int j = 0; j < 8; ++j) acc[i][j] = (acc[i][j] - m) * inv * gv[j] + bv[j];
  }
}

__global__ __launch_bounds__(256) void enc_node_kernel(
    const float* __restrict__ x,
    const float* __restrict__ W0, const float* __restrict__ b0,
    const float* __restrict__ W1, const float* __restrict__ b1,
    const float* __restrict__ W2, const float* __restrict__ b2,
    const float* __restrict__ g, const float* __restrict__ bt,
    float* __restrict__ hx, unsigned short* __restrict__ hx_bf) {
  __shared__ float As[64 * AP];
  __shared__ float Bs[128 * BP];
  int tid = threadIdx.x, ty = tid >> 4, tx = tid & 15;
  int n0 = blockIdx.x * 64;
#pragma unroll
  for (int p = 0; p < 8; ++p) {
    int idx = tid + p * 256;
    int r = idx >> 5, c = idx & 31;
    int n = min(n0 + r, NN - 1);
    As[r * AP + c] = (c < NODE_F) ? x[(size_t)n * NODE_F + c] : 0.f;
  }
  float acc[4][8];
  init_bias(acc, b0, tx);
  __syncthreads();
  load_B(Bs, W0, NODE_F, 0, tid);
  __syncthreads();
  fma32(As, Bs, acc, ty, tx, 0);

  __syncthreads(); store_relu(As, acc, ty, tx);
  layer_As(As, Bs, W1, b1, L, acc, tid, ty, tx);
  __syncthreads(); store_relu(As, acc, ty, tx);
  layer_As(As, Bs, W2, b2, L, acc, tid, ty, tx);
  lnorm(acc, g, bt, tx);
#pragma unroll
  for (int i = 0; i < 4; ++i) {
    int n = n0 + ty + 16 * i;
    if (n < NN)
#pragma unroll
      for (int j = 0; j < 8; ++j) {
        float v = acc[i][j];
        hx[(size_t)n * L + tx + 16 * j] = v;
        hx_bf[(size_t)n * L + tx + 16 * j] = f2bf(v);
      }
  }
}

__global__ __launch_bounds__(256) void dec_kernel(
    const float* __restrict__ hx,
    const float* __restrict__ W0, const float* __restrict__ b0,
    const float* __restrict__ W1, const float* __restrict__ b1,
    const float* __restrict__ W2, const float* __restrict__ b2,
    float* __restrict__ out) {
  __shared__ float As[64 * AP];
  __shared__ float Bs[128 * BP];
  __shared__ int nidx[64];
  int tid = threadIdx.x, ty = tid >> 4, tx = tid & 15;
  int n0 = blockIdx.x * 64;
  if (tid < 64) nidx[tid] = min(n0 + tid, NN - 1);
  __syncthreads();
  fillA_gather(As, hx, nidx, tid);
  float acc[4][8];
  layer_As(As, Bs, W0, b0, L, acc, tid, ty, tx);
  __syncthreads(); store_relu(As, acc, ty, tx);
  layer_As(As, Bs, W1, b1, L, acc, tid, ty, tx);
  __syncthreads(); store_relu(As, acc, ty, tx);
  __syncthreads();
  if (tid < 192) {
    int r = tid / 3, o = tid - (tid / 3) * 3;
    int n = n0 + r;
    if (n < NN) {
      float s = b2[o];
#pragma unroll 8
      for (int k = 0; k < L; ++k) s = fmaf(As[r * AP + k], W2[k * 3 + o], s);
      out[(size_t)n * 3 + o] = s;
    }
  }
}

// ================= launch =================

extern "C" void kernel_launch(void* const* d_in, const int* in_sizes, int n_in,
                              void* d_out, int out_size, void* d_ws, size_t ws_size,
                              hipStream_t stream) {
  (void)in_sizes; (void)n_in; (void)out_size; (void)ws_size;
  const float* x    = (const float*)d_in[0];
  const float* ea   = (const float*)d_in[1];
  const int*   ei   = (const int*)d_in[2];
  const float* enW0 = (const float*)d_in[3];  const float* enb0 = (const float*)d_in[4];
  const float* enW1 = (const float*)d_in[5];  const float* enb1 = (const float*)d_in[6];
  const float* enW2 = (const float*)d_in[7];  const float* enb2 = (const float*)d_in[8];
  const float* eng  = (const float*)d_in[9];  const float* enbt = (const float*)d_in[10];
  const float* eeW0 = (const float*)d_in[11]; const float* eeb0 = (const float*)d_in[12];
  const float* eeW1 = (const float*)d_in[13]; const float* eeb1 = (const float*)d_in[14];
  const float* eeW2 = (const float*)d_in[15]; const float* eeb2 = (const float*)d_in[16];
  const float* eeg  = (const float*)d_in[17]; const float* eebt = (const float*)d_in[18];
  const float* peW0 = (const float*)d_in[19]; const float* peb0 = (const float*)d_in[20];
  const float* peW1 = (const float*)d_in[21]; const float* peb1 = (const float*)d_in[22];
  const float* peW2 = (const float*)d_in[23]; const float* peb2 = (const float*)d_in[24];
  const float* peg  = (const float*)d_in[25]; const float* pebt = (const float*)d_in[26];
  const float* pnW0 = (const float*)d_in[27]; const float* pnb0 = (const float*)d_in[28];
  const float* pnW1 = (const float*)d_in[29]; const float* pnb1 = (const float*)d_in[30];
  const float* pnW2 = (const float*)d_in[31]; const float* pnb2 = (const float*)d_in[32];
  const float* png  = (const float*)d_in[33]; const float* pnbt = (const float*)d_in[34];
  const float* dW0  = (const float*)d_in[35]; const float* db0  = (const float*)d_in[36];
  const float* dW1  = (const float*)d_in[37]; const float* db1  = (const float*)d_in[38];
  const float* dW2  = (const float*)d_in[39]; const float* db2  = (const float*)d_in[40];

  const size_t F_HX = (size_t)NN * L, F_HE = (size_t)NE * L;
  const size_t W_PE = 819200, W_PN = 655360, W_EE = 32768;

  float* hx = (float*)d_ws;                              // NN*L fp32
  unsigned short* he_bf  = (unsigned short*)(hx + F_HX); // NE*L bf16
  unsigned short* ue_bf  = he_bf + F_HE;                 // NE*L bf16
  unsigned short* hx_bf  = ue_bf + F_HE;                 // NN*L bf16
  unsigned short* wt_pe  = hx_bf + F_HX;
  unsigned short* wt_pn  = wt_pe + W_PE;
  unsigned short* wt_ee  = wt_pn + W_PN;
  int* cnt = (int*)(wt_ee + W_EE);
  int* off = cnt + NN;
  int* cur = off + NN + 1;
  int* eid = cur + NN;

  dim3 blk(256);
  int grid_n = (NN + 63) / 64;   // 157
  int grid_e = (NE + 63) / 64;   // 1563

  wprep_kernel<<<(10 * 81920 + 255) / 256, blk, 0, stream>>>(peW0, peW1, peW2, wt_pe, 384, 10);
  wprep_kernel<<<(10 * 65536 + 255) / 256, blk, 0, stream>>>(pnW0, pnW1, pnW2, wt_pn, 256, 10);
  tprep_kernel<<<128, blk, 0, stream>>>(eeW1, eeW2, wt_ee);

  hipMemsetAsync(cnt, 0, (size_t)NN * 4, stream);
  deg_kernel<<<(NE + 255) / 256, blk, 0, stream>>>(ei, cnt);
  scan_kernel<<<1, blk, 0, stream>>>(cnt, off, cur);
  scatter_kernel<<<(NE + 255) / 256, blk, 0, stream>>>(ei, cur, eid);

  enc_node_kernel<<<grid_n, blk, 0, stream>>>(x, enW0, enb0, enW1, enb1, enW2, enb2, eng, enbt, hx, hx_bf);
  enc_edge_mfma<<<grid_e, blk, 0, stream>>>(ea, eeW0, eeb0, wt_ee, eeb1, wt_ee + 16384, eeb2, eeg, eebt, he_bf);

  for (int s = 0; s < STEPS; ++s) {
    const unsigned short* pe = wt_pe + (size_t)s * 81920;
    const unsigned short* pn = wt_pn + (size_t)s * 65536;
    edge_step_mfma<<<grid_e, blk, 0, stream>>>(
        hx_bf, he_bf, ue_bf, ei,
        pe,                 peb0 + (size_t)s * L,
        pe + 49152,         peb1 + (size_t)s * L,
        pe + 49152 + 16384, peb2 + (size_t)s * L,
        peg + (size_t)s * L, pebt + (size_t)s * L);
    node_step_mfma<<<grid_n, blk, 0, stream>>>(
        hx, hx_bf, ue_bf, off, eid,
        pn,                 pnb0 + (size_t)s * L,
        pn + 32768,         pnb1 + (size_t)s * L,
        pn + 32768 + 16384, pnb2 + (size_t)s * L,
        png + (size_t)s * L, pnbt + (size_t)s * L);
  }

  dec_kernel<<<grid_n, blk, 0, stream>>>(hx, dW0, db0, dW1, db1, dW2, db2, (float*)d_out);
}

// Round 14
// 920.950 us; speedup vs baseline: 1.5263x; 1.0422x over previous
//
#include <hip/hip_runtime.h>

// EncodeProcessDecode (GNS): N=10000 nodes, E=100000 edges, S=10 steps, L=H=128.
// Round 14: edge = exact R9 (proven 55.5us; setprio dropped — R13 showed neutral).
// node_step re-tiled: 32 nodes/block, grid 313 (was 64/157 -> 99 CUs idle, 1
// lone block per CU serializing 12 phases). Wave tile 16x64 (acc[4]), LDS
// 69.6->52.2 KB. Same CSR order + fp32 accum -> numerics unchanged.

#define NN 10000
#define NE 100000
#define STEPS 10
#define NODE_F 30
#define EDGE_F 4
#define L 128
#define AP 132   // fp32 helper LDS stride (encoder-node / decoder)
#define BP 36

#define WS_STRIDE 136   // bf16 elems per LDS row: 128 + 8 pad
#define AB_STRIDE 136

typedef __bf16 bf16x8 __attribute__((ext_vector_type(8)));
typedef float f32x4 __attribute__((ext_vector_type(4)));

__device__ __forceinline__ unsigned short f2bf(float f) {
  __bf16 b = (__bf16)f;
  return __builtin_bit_cast(unsigned short, b);
}
__device__ __forceinline__ float bf2f(unsigned short u) {
  return __builtin_bit_cast(float, (unsigned)u << 16);
}

// ================= staging =================

__device__ __forceinline__ void stage_W(unsigned short* __restrict__ Ws,
                                        const unsigned short* __restrict__ Wt,
                                        int K, int sec, int tid) {
#pragma unroll
  for (int p = 0; p < 8; ++p) {
    int u = tid + p * 256;
    int n = u >> 4, kk = u & 15;
    uint4 v = *(const uint4*)(Wt + (size_t)n * K + sec * 128 + kk * 8);
    *(uint4*)&Ws[n * WS_STRIDE + kk * 8] = v;
  }
}

// ================= MFMA helpers (2x4: wave tile 32x64) =================

__device__ __forceinline__ void init_acc(f32x4 acc[2][4], const float* __restrict__ b,
                                         int wcol, int l16) {
#pragma unroll
  for (int j = 0; j < 4; ++j) {
    float bv = b[wcol + j * 16 + l16];
#pragma unroll
    for (int i = 0; i < 2; ++i) acc[i][j] = f32x4{bv, bv, bv, bv};
  }
}

__device__ __forceinline__ void layer_gbf(const unsigned short* __restrict__ ap0,
                                          const unsigned short* __restrict__ ap1,
                                          const unsigned short* __restrict__ Ws,
                                          f32x4 acc[2][4], int wcol, int l4, int l16) {
#pragma unroll
  for (int kk = 0; kk < 4; ++kk) {
    bf16x8 af[2];
    af[0] = *(const bf16x8*)(ap0 + kk * 32 + l4 * 8);
    af[1] = *(const bf16x8*)(ap1 + kk * 32 + l4 * 8);
#pragma unroll
    for (int j = 0; j < 4; ++j) {
      bf16x8 bv = *(const bf16x8*)&Ws[(wcol + j * 16 + l16) * WS_STRIDE + kk * 32 + l4 * 8];
#pragma unroll
      for (int i = 0; i < 2; ++i)
        acc[i][j] = __builtin_amdgcn_mfma_f32_16x16x32_bf16(af[i], bv, acc[i][j], 0, 0, 0);
    }
  }
}

__device__ __forceinline__ void layer_lds(const unsigned short* __restrict__ Ab,
                                          const unsigned short* __restrict__ Ws,
                                          f32x4 acc[2][4], int wrow, int wcol, int l4, int l16) {
#pragma unroll
  for (int kk = 0; kk < 4; ++kk) {
    bf16x8 af[2];
#pragma unroll
    for (int i = 0; i < 2; ++i)
      af[i] = *(const bf16x8*)&Ab[(wrow + i * 16 + l16) * AB_STRIDE + kk * 32 + l4 * 8];
#pragma unroll
    for (int j = 0; j < 4; ++j) {
      bf16x8 bv = *(const bf16x8*)&Ws[(wcol + j * 16 + l16) * WS_STRIDE + kk * 32 + l4 * 8];
#pragma unroll
      for (int i = 0; i < 2; ++i)
        acc[i][j] = __builtin_amdgcn_mfma_f32_16x16x32_bf16(af[i], bv, acc[i][j], 0, 0, 0);
    }
  }
}

__device__ __forceinline__ void relu_to_Ab(unsigned short* __restrict__ Ab, f32x4 acc[2][4],
                                           int wrow, int wcol, int l4, int l16) {
#pragma unroll
  for (int i = 0; i < 2; ++i)
#pragma unroll
    for (int j = 0; j < 4; ++j)
#pragma unroll
      for (int r = 0; r < 4; ++r) {
        int row = wrow + i * 16 + l4 * 4 + r;
        int col = wcol + j * 16 + l16;
        Ab[row * AB_STRIDE + col] = f2bf(fmaxf(acc[i][j][r], 0.f));
      }
}

__device__ __forceinline__ void ln_partials(const f32x4 acc[2][4], float ps[2][4], float ps2[2][4]) {
#pragma unroll
  for (int i = 0; i < 2; ++i)
#pragma unroll
    for (int r = 0; r < 4; ++r) {
      float s = 0.f, s2 = 0.f;
#pragma unroll
      for (int j = 0; j < 4; ++j) { float v = acc[i][j][r]; s += v; s2 += v * v; }
#pragma unroll
      for (int off = 1; off < 16; off <<= 1) {
        s += __shfl_xor(s, off, 64);
        s2 += __shfl_xor(s2, off, 64);
      }
      ps[i][r] = s; ps2[i][r] = s2;
    }
}

// ---- 1x4 variants (node: wave tile 16x64) ----

__device__ __forceinline__ void init_acc1(f32x4 acc[4], const float bv[4]) {
#pragma unroll
  for (int j = 0; j < 4; ++j) acc[j] = f32x4{bv[j], bv[j], bv[j], bv[j]};
}

__device__ __forceinline__ void layer_gbf1(const unsigned short* __restrict__ ap,
                                           const unsigned short* __restrict__ Ws,
                                           f32x4 acc[4], int wcol, int l4, int l16) {
#pragma unroll
  for (int kk = 0; kk < 4; ++kk) {
    bf16x8 af = *(const bf16x8*)(ap + kk * 32 + l4 * 8);
#pragma unroll
    for (int j = 0; j < 4; ++j) {
      bf16x8 bv = *(const bf16x8*)&Ws[(wcol + j * 16 + l16) * WS_STRIDE + kk * 32 + l4 * 8];
      acc[j] = __builtin_amdgcn_mfma_f32_16x16x32_bf16(af, bv, acc[j], 0, 0, 0);
    }
  }
}

__device__ __forceinline__ void layer_lds1(const unsigned short* __restrict__ Ab,
                                           const unsigned short* __restrict__ Ws,
                                           f32x4 acc[4], int wrow, int wcol, int l4, int l16) {
#pragma unroll
  for (int kk = 0; kk < 4; ++kk) {
    bf16x8 af = *(const bf16x8*)&Ab[(wrow + l16) * AB_STRIDE + kk * 32 + l4 * 8];
#pragma unroll
    for (int j = 0; j < 4; ++j) {
      bf16x8 bv = *(const bf16x8*)&Ws[(wcol + j * 16 + l16) * WS_STRIDE + kk * 32 + l4 * 8];
      acc[j] = __builtin_amdgcn_mfma_f32_16x16x32_bf16(af, bv, acc[j], 0, 0, 0);
    }
  }
}

__device__ __forceinline__ void relu_to_Ab1(unsigned short* __restrict__ Ab, f32x4 acc[4],
                                            int wrow, int wcol, int l4, int l16) {
#pragma unroll
  for (int j = 0; j < 4; ++j)
#pragma unroll
    for (int r = 0; r < 4; ++r) {
      int row = wrow + l4 * 4 + r;
      int col = wcol + j * 16 + l16;
      Ab[row * AB_STRIDE + col] = f2bf(fmaxf(acc[j][r], 0.f));
    }
}

__device__ __forceinline__ void ln_partials1(const f32x4 acc[4], float ps[4], float ps2[4]) {
#pragma unroll
  for (int r = 0; r < 4; ++r) {
    float s = 0.f, s2 = 0.f;
#pragma unroll
    for (int j = 0; j < 4; ++j) { float v = acc[j][r]; s += v; s2 += v * v; }
#pragma unroll
    for (int off = 1; off < 16; off <<= 1) {
      s += __shfl_xor(s, off, 64);
      s2 += __shfl_xor(s2, off, 64);
    }
    ps[r] = s; ps2[r] = s2;
  }
}

// ================= CSR prep =================

__global__ __launch_bounds__(256) void deg_kernel(const int* __restrict__ ei, int* __restrict__ cnt) {
  int e = blockIdx.x * 256 + threadIdx.x;
  if (e < NE) atomicAdd(&cnt[ei[NE + e]], 1);
}

__global__ __launch_bounds__(256) void scan_kernel(const int* __restrict__ cnt,
                                                   int* __restrict__ off, int* __restrict__ cur) {
  __shared__ int sums[256];
  int t = threadIdx.x;
  int base = t * 40;   // 256*40 = 10240 >= NN
  int local = 0;
  for (int i = 0; i < 40; ++i) { int n = base + i; if (n < NN) local += cnt[n]; }
  sums[t] = local;
  __syncthreads();
  int val = local;
  for (int d = 1; d < 256; d <<= 1) {
    int add = (t >= d) ? sums[t - d] : 0;
    __syncthreads();
    sums[t] += add;
    __syncthreads();
  }
  int run = sums[t] - val;
  for (int i = 0; i < 40; ++i) {
    int n = base + i;
    if (n < NN) { off[n] = run; cur[n] = run; run += cnt[n]; }
  }
  if (t == 255) off[NN] = sums[255];
}

__global__ __launch_bounds__(256) void scatter_kernel(const int* __restrict__ ei,
                                                      int* __restrict__ cur, int* __restrict__ eid) {
  int e = blockIdx.x * 256 + threadIdx.x;
  if (e < NE) { int p = atomicAdd(&cur[ei[NE + e]], 1); eid[p] = e; }
}

// ================= edge step (exact R9) =================

__global__ __launch_bounds__(256) void edge_step_mfma(
    const unsigned short* __restrict__ hx_bf, unsigned short* __restrict__ he_bf,
    unsigned short* __restrict__ ue_bf,
    const int* __restrict__ ei,
    const unsigned short* __restrict__ W0t, const float* __restrict__ b0,
    const unsigned short* __restrict__ W1t, const float* __restrict__ b1,
    const unsigned short* __restrict__ W2t, const float* __restrict__ b2,
    const float* __restrict__ g, const float* __restrict__ bt) {
  __shared__ __align__(16) unsigned short Ws[128 * WS_STRIDE];
  __shared__ __align__(16) unsigned short Ab[64 * AB_STRIDE];
  __shared__ int sidx[64], didx[64];
  int tid = threadIdx.x;
  int w = tid >> 6, lane = tid & 63;
  int l4 = lane >> 4, l16 = lane & 15;
  int wrow = (w >> 1) * 32, wcol = (w & 1) * 64;
  int e0 = blockIdx.x * 64;
  if (tid < 64) {
    int e = min(e0 + tid, NE - 1);
    sidx[tid] = ei[e];
    didx[tid] = ei[NE + e];
  }
  f32x4 acc[2][4];
  init_acc(acc, b0, wcol, l16);
  __syncthreads();
  for (int sec = 0; sec < 3; ++sec) {
    stage_W(Ws, W0t, 384, sec, tid);
    const unsigned short* ap[2];
#pragma unroll
    for (int i = 0; i < 2; ++i) {
      int r = wrow + i * 16 + l16;
      if (sec == 0)      ap[i] = hx_bf + (size_t)sidx[r] * L;
      else if (sec == 1) ap[i] = hx_bf + (size_t)didx[r] * L;
      else               ap[i] = he_bf + (size_t)min(e0 + r, NE - 1) * L;
    }
    __syncthreads();
    layer_gbf(ap[0], ap[1], Ws, acc, wcol, l4, l16);
    __syncthreads();
  }
  relu_to_Ab(Ab, acc, wrow, wcol, l4, l16);
  stage_W(Ws, W1t, 128, 0, tid);
  init_acc(acc, b1, wcol, l16);
  __syncthreads();
  layer_lds(Ab, Ws, acc, wrow, wcol, l4, l16);
  __syncthreads();
  relu_to_Ab(Ab, acc, wrow, wcol, l4, l16);
  stage_W(Ws, W2t, 128, 0, tid);
  init_acc(acc, b2, wcol, l16);
  __syncthreads();
  layer_lds(Ab, Ws, acc, wrow, wcol, l4, l16);
  float ps[2][4], ps2[2][4];
  ln_partials(acc, ps, ps2);
  __syncthreads();
  float* red = (float*)Ab;
  if (l16 == 0) {
#pragma unroll
    for (int i = 0; i < 2; ++i)
#pragma unroll
      for (int r = 0; r < 4; ++r) {
        int row = wrow + i * 16 + l4 * 4 + r;
        red[(w & 1) * 128 + row * 2 + 0] = ps[i][r];
        red[(w & 1) * 128 + row * 2 + 1] = ps2[i][r];
      }
  }
  __syncthreads();
  float gv[4], btv[4];
#pragma unroll
  for (int j = 0; j < 4; ++j) {
    int col = wcol + j * 16 + l16;
    gv[j] = g[col]; btv[j] = bt[col];
  }
#pragma unroll
  for (int i = 0; i < 2; ++i)
#pragma unroll
    for (int r = 0; r < 4; ++r) {
      int row = wrow + i * 16 + l4 * 4 + r;
      float s  = red[row * 2]     + red[128 + row * 2];
      float s2 = red[row * 2 + 1] + red[128 + row * 2 + 1];
      float m = s * (1.f / 128.f);
      float inv = rsqrtf(s2 * (1.f / 128.f) - m * m + 1e-5f);
      int e = e0 + row;
      if (e < NE) {
        size_t hoff = (size_t)e * L;
#pragma unroll
        for (int j = 0; j < 4; ++j) {
          int col = wcol + j * 16 + l16;
          float u = (acc[i][j][r] - m) * inv * gv[j] + btv[j];
          unsigned short old = he_bf[hoff + col];
          he_bf[hoff + col] = f2bf(bf2f(old) + u);
          ue_bf[hoff + col] = f2bf(u);
        }
      }
    }
}

// ================= node step: 32-node tiles, fused CSR aggregation =============

__global__ __launch_bounds__(256) void node_step_mfma(
    float* __restrict__ hx, unsigned short* __restrict__ hx_bf,
    const unsigned short* __restrict__ ue_bf,
    const int* __restrict__ off, const int* __restrict__ eid,
    const unsigned short* __restrict__ W0t, const float* __restrict__ b0,
    const unsigned short* __restrict__ W1t, const float* __restrict__ b1,
    const unsigned short* __restrict__ W2t, const float* __restrict__ b2,
    const float* __restrict__ g, const float* __restrict__ bt) {
  __shared__ __align__(16) unsigned short Ws[128 * WS_STRIDE];   // 34.8 KB
  __shared__ __align__(16) unsigned short Ab[32 * AB_STRIDE];    // 8.7 KB
  __shared__ __align__(16) unsigned short Ag[32 * AB_STRIDE];    // 8.7 KB
  int tid = threadIdx.x;
  int w = tid >> 6, lane = tid & 63;
  int l4 = lane >> 4, l16 = lane & 15;
  int wrow = (w >> 1) * 16, wcol = (w & 1) * 64;   // 4 waves: 2 row-groups x 2 col-groups
  int n0 = blockIdx.x * 32;
  // ---- phase A: agg rows into Ag (fp32 accum, CSR order) ----
  {
    int r = tid >> 3;                 // node row 0..31
    int cseg = (tid & 7) * 16;        // 16 cols per thread
    int n = n0 + r;
    float a[16];
#pragma unroll
    for (int q = 0; q < 16; ++q) a[q] = 0.f;
    if (n < NN) {
      int p0 = off[n], p1 = off[n + 1];
      for (int p = p0; p < p1; ++p) {
        const unsigned short* row = ue_bf + (size_t)eid[p] * L + cseg;
#pragma unroll
        for (int q = 0; q < 2; ++q) {
          uint4 v = *(const uint4*)(row + q * 8);
          a[q * 8 + 0] += __builtin_bit_cast(float, v.x << 16);
          a[q * 8 + 1] += __builtin_bit_cast(float, v.x & 0xffff0000u);
          a[q * 8 + 2] += __builtin_bit_cast(float, v.y << 16);
          a[q * 8 + 3] += __builtin_bit_cast(float, v.y & 0xffff0000u);
          a[q * 8 + 4] += __builtin_bit_cast(float, v.z << 16);
          a[q * 8 + 5] += __builtin_bit_cast(float, v.z & 0xffff0000u);
          a[q * 8 + 6] += __builtin_bit_cast(float, v.w << 16);
          a[q * 8 + 7] += __builtin_bit_cast(float, v.w & 0xffff0000u);
        }
      }
    }
#pragma unroll
    for (int q = 0; q < 8; ++q) {
      unsigned o = (unsigned)f2bf(a[2 * q]) | ((unsigned)f2bf(a[2 * q + 1]) << 16);
      *(unsigned*)&Ag[r * AB_STRIDE + cseg + 2 * q] = o;
    }
  }
  float bv0[4], bv1[4], bv2[4], gv[4], btv[4];
#pragma unroll
  for (int j = 0; j < 4; ++j) {
    int c = wcol + j * 16 + l16;
    bv0[j] = b0[c]; bv1[j] = b1[c]; bv2[j] = b2[c]; gv[j] = g[c]; btv[j] = bt[c];
  }
  stage_W(Ws, W0t, 256, 0, tid);
  f32x4 acc[4];
  init_acc1(acc, bv0);
  __syncthreads();                   // Ws(sec0) + Ag ready
  // ---- layer0 sec0: A = hx rows (global bf16) ----
  {
    const unsigned short* ap = hx_bf + (size_t)min(n0 + wrow + l16, NN - 1) * L;
    layer_gbf1(ap, Ws, acc, wcol, l4, l16);
  }
  __syncthreads();
  stage_W(Ws, W0t, 256, 1, tid);
  __syncthreads();                   // Ws(sec1) ready
  // ---- layer0 sec1: A = Ag (LDS) ----
  layer_lds1(Ag, Ws, acc, wrow, wcol, l4, l16);
  __syncthreads();
  // ---- layer1 ----
  relu_to_Ab1(Ab, acc, wrow, wcol, l4, l16);
  stage_W(Ws, W1t, 128, 0, tid);
  init_acc1(acc, bv1);
  __syncthreads();
  layer_lds1(Ab, Ws, acc, wrow, wcol, l4, l16);
  __syncthreads();
  // ---- layer2 ----
  relu_to_Ab1(Ab, acc, wrow, wcol, l4, l16);
  stage_W(Ws, W2t, 128, 0, tid);
  init_acc1(acc, bv2);
  __syncthreads();
  layer_lds1(Ab, Ws, acc, wrow, wcol, l4, l16);
  // ---- LayerNorm + residual ----
  float ps[4], ps2[4];
  ln_partials1(acc, ps, ps2);
  __syncthreads();                   // Ab reads done; red overlays Ab
  float* red = (float*)Ab;           // [2 col-halves][32 rows][2] = 128 floats
  if (l16 == 0) {
#pragma unroll
    for (int r = 0; r < 4; ++r) {
      int row = wrow + l4 * 4 + r;
      red[(w & 1) * 64 + row * 2 + 0] = ps[r];
      red[(w & 1) * 64 + row * 2 + 1] = ps2[r];
    }
  }
  __syncthreads();
#pragma unroll
  for (int r = 0; r < 4; ++r) {
    int row = wrow + l4 * 4 + r;
    float s  = red[row * 2]     + red[64 + row * 2];
    float s2 = red[row * 2 + 1] + red[64 + row * 2 + 1];
    float m = s * (1.f / 128.f);
    float inv = rsqrtf(s2 * (1.f / 128.f) - m * m + 1e-5f);
    int n = n0 + row;
    if (n < NN) {
#pragma unroll
      for (int j = 0; j < 4; ++j) {
        int col = wcol + j * 16 + l16;
        float un = (acc[j][r] - m) * inv * gv[j] + btv[j];
        float nv = hx[(size_t)n * L + col] + un;
        hx[(size_t)n * L + col] = nv;
        hx_bf[(size_t)n * L + col] = f2bf(nv);
      }
    }
  }
}

// ================= edge encoder (R9) =================

__global__ __launch_bounds__(256) void enc_edge_mfma(
    const float* __restrict__ ea,
    const float* __restrict__ W0, const float* __restrict__ b0,
    const unsigned short* __restrict__ W1t, const float* __restrict__ b1,
    const unsigned short* __restrict__ W2t, const float* __restrict__ b2,
    const float* __restrict__ g, const float* __restrict__ bt,
    unsigned short* __restrict__ he_bf) {
  __shared__ __align__(16) unsigned short Ws[128 * WS_STRIDE];
  __shared__ __align__(16) unsigned short Ab[64 * AB_STRIDE];
  int tid = threadIdx.x;
  int w = tid >> 6, lane = tid & 63;
  int l4 = lane >> 4, l16 = lane & 15;
  int wrow = (w >> 1) * 32, wcol = (w & 1) * 64;
  int e0 = blockIdx.x * 64;
  {
    int row = tid >> 2, cbase = (tid & 3) * 32;
    int e = min(e0 + row, NE - 1);
    float4 eav = *(const float4*)&ea[(size_t)e * 4];
#pragma unroll
    for (int c = 0; c < 32; ++c) {
      int col = cbase + c;
      float sum = b0[col] + eav.x * W0[col] + eav.y * W0[128 + col] +
                  eav.z * W0[256 + col] + eav.w * W0[384 + col];
      Ab[row * AB_STRIDE + col] = f2bf(fmaxf(sum, 0.f));
    }
  }
  stage_W(Ws, W1t, 128, 0, tid);
  f32x4 acc[2][4];
  init_acc(acc, b1, wcol, l16);
  __syncthreads();
  layer_lds(Ab, Ws, acc, wrow, wcol, l4, l16);
  __syncthreads();
  relu_to_Ab(Ab, acc, wrow, wcol, l4, l16);
  stage_W(Ws, W2t, 128, 0, tid);
  init_acc(acc, b2, wcol, l16);
  __syncthreads();
  layer_lds(Ab, Ws, acc, wrow, wcol, l4, l16);
  float ps[2][4], ps2[2][4];
  ln_partials(acc, ps, ps2);
  __syncthreads();
  float* red = (float*)Ws;
  if (l16 == 0) {
#pragma unroll
    for (int i = 0; i < 2; ++i)
#pragma unroll
      for (int r = 0; r < 4; ++r) {
        int row = wrow + i * 16 + l4 * 4 + r;
        red[(w & 1) * 128 + row * 2 + 0] = ps[i][r];
        red[(w & 1) * 128 + row * 2 + 1] = ps2[i][r];
      }
  }
  __syncthreads();
  float gv[4], btv[4];
#pragma unroll
  for (int j = 0; j < 4; ++j) {
    int col = wcol + j * 16 + l16;
    gv[j] = g[col]; btv[j] = bt[col];
  }
#pragma unroll
  for (int i = 0; i < 2; ++i)
#pragma unroll
    for (int r = 0; r < 4; ++r) {
      int row = wrow + i * 16 + l4 * 4 + r;
      float s  = red[row * 2]     + red[128 + row * 2];
      float s2 = red[row * 2 + 1] + red[128 + row * 2 + 1];
      float m = s * (1.f / 128.f);
      float inv = rsqrtf(s2 * (1.f / 128.f) - m * m + 1e-5f);
      int e = e0 + row;
      if (e < NE) {
#pragma unroll
        for (int j = 0; j < 4; ++j) {
          int col = wcol + j * 16 + l16;
          he_bf[(size_t)e * L + col] = f2bf((acc[i][j][r] - m) * inv * gv[j] + btv[j]);
        }
      }
    }
}

// ================= weight prep =================

__global__ __launch_bounds__(256) void wprep_kernel(
    const float* __restrict__ W0, const float* __restrict__ W1, const float* __restrict__ W2,
    unsigned short* __restrict__ out, int K0, int steps) {
  int per_step = 128 * (K0 + 256);
  int idx = blockIdx.x * 256 + threadIdx.x;
  if (idx >= steps * per_step) return;
  int s = idx / per_step, r = idx - s * per_step;
  float v;
  if (r < 128 * K0) {
    int n = r / K0, k = r - n * K0;
    v = W0[(size_t)s * K0 * 128 + (size_t)k * 128 + n];
  } else {
    r -= 128 * K0;
    const float* W = (r < 16384) ? W1 : W2;
    r &= 16383;
    int n = r >> 7, k = r & 127;
    v = W[(size_t)s * 16384 + k * 128 + n];
  }
  out[idx] = f2bf(v);
}

__global__ __launch_bounds__(256) void tprep_kernel(
    const float* __restrict__ W1, const float* __restrict__ W2, unsigned short* __restrict__ out) {
  int idx = blockIdx.x * 256 + threadIdx.x;   // < 32768
  const float* W = (idx < 16384) ? W1 : W2;
  int r = idx & 16383;
  int n = r >> 7, k = r & 127;
  out[idx] = f2bf(W[k * 128 + n]);
}

// ================= fp32 helpers (encoder-node / decoder) =================

__device__ __forceinline__ void load_B(float* __restrict__ Bs, const float* __restrict__ W,
                                       int K, int k0, int tid) {
#pragma unroll
  for (int p = 0; p < 16; ++p) {
    int idx = tid + p * 256;
    int kk = idx >> 7;
    int c = idx & 127;
    float v = 0.f;
    if (k0 + kk < K) v = W[(size_t)(k0 + kk) * L + c];
    Bs[c * BP + kk] = v;
  }
}

__device__ __forceinline__ void fma32(const float* __restrict__ As, const float* __restrict__ Bs,
                                      float acc[4][8], int ty, int tx, int koff) {
#pragma unroll
  for (int kk = 0; kk < 32; kk += 4) {
    float4 a[4];
    float4 b[8];
#pragma unroll
    for (int i = 0; i < 4; ++i)
      a[i] = *(const float4*)&As[(ty + 16 * i) * AP + koff + kk];
#pragma unroll
    for (int j = 0; j < 8; ++j)
      b[j] = *(const float4*)&Bs[(tx + 16 * j) * BP + kk];
#pragma unroll
    for (int i = 0; i < 4; ++i)
#pragma unroll
      for (int j = 0; j < 8; ++j) {
        acc[i][j] = fmaf(a[i].x, b[j].x, acc[i][j]);
        acc[i][j] = fmaf(a[i].y, b[j].y, acc[i][j]);
        acc[i][j] = fmaf(a[i].z, b[j].z, acc[i][j]);
        acc[i][j] = fmaf(a[i].w, b[j].w, acc[i][j]);
      }
  }
}

__device__ __forceinline__ void init_bias(float acc[4][8], const float* __restrict__ b, int tx) {
#pragma unroll
  for (int j = 0; j < 8; ++j) {
    float bv = b[tx + 16 * j];
#pragma unroll
    for (int i = 0; i < 4; ++i) acc[i][j] = bv;
  }
}

__device__ __forceinline__ void store_relu(float* __restrict__ As, float acc[4][8], int ty, int tx) {
#pragma unroll
  for (int i = 0; i < 4; ++i)
#pragma unroll
    for (int j = 0; j < 8; ++j)
      As[(ty + 16 * i) * AP + tx + 16 * j] = fmaxf(acc[i][j], 0.f);
}

__device__ __forceinline__ void layer_As(const float* __restrict__ As, float* __restrict__ Bs,
                                         const float* __restrict__ W, const float* __restrict__ bias,
                                         int K, float acc[4][8], int tid, int ty, int tx) {
  init_bias(acc, bias, tx);
  int nc = (K + 31) >> 5;
  for (int bc = 0; bc < nc; ++bc) {
    __syncthreads();
    load_B(Bs, W, K, bc * 32, tid);
    __syncthreads();
    fma32(As, Bs, acc, ty, tx, bc * 32);
  }
}

__device__ __forceinline__ void fillA_gather(float* __restrict__ As, const float* __restrict__ base,
                                             const int* __restrict__ ridx, int tid) {
#pragma unroll
  for (int p = 0; p < 8; ++p) {
    int idx = tid + p * 256;
    int r = idx >> 5;
    int c4 = idx & 31;
    float4 v = *(const float4*)&base[(size_t)ridx[r] * L + c4 * 4];
    *(float4*)&As[r * AP + c4 * 4] = v;
  }
}

__device__ __forceinline__ void lnorm(float acc[4][8], const float* __restrict__ g,
                                      const float* __restrict__ bt, int tx) {
  float gv[8], bv[8];
#pragma unroll
  for (int j = 0; j < 8; ++j) { gv[j] = g[tx + 16 * j]; bv[j] = bt[tx + 16 * j]; }
#pragma unroll
  for (int i = 0; i < 4; ++i) {
    float s = 0.f, s2 = 0.f;
#pragma unroll
    for (int j = 0; j < 8; ++j) { s += acc[i][j]; s2 += acc[i][j] * acc[i][j]; }
#pragma unroll
    for (int off = 1; off < 16; off <<= 1) {
      s  += __shfl_xor(s, off, 64);
      s2 += __shfl_xor(s2, off, 64);
    }
    float m = s * (1.f / 128.f);
    float var = s2 * (1.f / 128.f) - m * m;
    float inv = rsqrtf(var + 1e-5f);
#pragma unroll
    for (int j = 0; j < 8; ++j) acc[i][j] = (acc[i][j] - m) * inv * gv[j] + bv[j];
  }
}

__global__ __launch_bounds__(256) void enc_node_kernel(
    const float* __restrict__ x,
    const float* __restrict__ W0, const float* __restrict__ b0,
    const float* __restrict__ W1, const float* __restrict__ b1,
    const float* __restrict__ W2, const float* __restrict__ b2,
    const float* __restrict__ g, const float* __restrict__ bt,
    float* __restrict__ hx, unsigned short* __restrict__ hx_bf) {
  __shared__ float As[64 * AP];
  __shared__ float Bs[128 * BP];
  int tid = threadIdx.x, ty = tid >> 4, tx = tid & 15;
  int n0 = blockIdx.x * 64;
#pragma unroll
  for (int p = 0; p < 8; ++p) {
    int idx = tid + p * 256;
    int r = idx >> 5, c = idx & 31;
    int n = min(n0 + r, NN - 1);
    As[r * AP + c] = (c < NODE_F) ? x[(size_t)n * NODE_F + c] : 0.f;
  }
  float acc[4][8];
  init_bias(acc, b0, tx);
  __syncthreads();
  load_B(Bs, W0, NODE_F, 0, tid);
  __syncthreads();
  fma32(As, Bs, acc, ty, tx, 0);

  __syncthreads(); store_relu(As, acc, ty, tx);
  layer_As(As, Bs, W1, b1, L, acc, tid, ty, tx);
  __syncthreads(); store_relu(As, acc, ty, tx);
  layer_As(As, Bs, W2, b2, L, acc, tid, ty, tx);
  lnorm(acc, g, bt, tx);
#pragma unroll
  for (int i = 0; i < 4; ++i) {
    int n = n0 + ty + 16 * i;
    if (n < NN)
#pragma unroll
      for (int j = 0; j < 8; ++j) {
        float v = acc[i][j];
        hx[(size_t)n * L + tx + 16 * j] = v;
        hx_bf[(size_t)n * L + tx + 16 * j] = f2bf(v);
      }
  }
}

__global__ __launch_bounds__(256) void dec_kernel(
    const float* __restrict__ hx,
    const float* __restrict__ W0, const float* __restrict__ b0,
    const float* __restrict__ W1, const float* __restrict__ b1,
    const float* __restrict__ W2, const float* __restrict__ b2,
    float* __restrict__ out) {
  __shared__ float As[64 * AP];
  __shared__ float Bs[128 * BP];
  __shared__ int nidx[64];
  int tid = threadIdx.x, ty = tid >> 4, tx = tid & 15;
  int n0 = blockIdx.x * 64;
  if (tid < 64) nidx[tid] = min(n0 + tid, NN - 1);
  __syncthreads();
  fillA_gather(As, hx, nidx, tid);
  float acc[4][8];
  layer_As(As, Bs, W0, b0, L, acc, tid, ty, tx);
  __syncthreads(); store_relu(As, acc, ty, tx);
  layer_As(As, Bs, W1, b1, L, acc, tid, ty, tx);
  __syncthreads(); store_relu(As, acc, ty, tx);
  __syncthreads();
  if (tid < 192) {
    int r = tid / 3, o = tid - (tid / 3) * 3;
    int n = n0 + r;
    if (n < NN) {
      float s = b2[o];
#pragma unroll 8
      for (int k = 0; k < L; ++k) s = fmaf(As[r * AP + k], W2[k * 3 + o], s);
      out[(size_t)n * 3 + o] = s;
    }
  }
}

// ================= launch =================

extern "C" void kernel_launch(void* const* d_in, const int* in_sizes, int n_in,
                              void* d_out, int out_size, void* d_ws, size_t ws_size,
                              hipStream_t stream) {
  (void)in_sizes; (void)n_in; (void)out_size; (void)ws_size;
  const float* x    = (const float*)d_in[0];
  const float* ea   = (const float*)d_in[1];
  const int*   ei   = (const int*)d_in[2];
  const float* enW0 = (const float*)d_in[3];  const float* enb0 = (const float*)d_in[4];
  const float* enW1 = (const float*)d_in[5];  const float* enb1 = (const float*)d_in[6];
  const float* enW2 = (const float*)d_in[7];  const float* enb2 = (const float*)d_in[8];
  const float* eng  = (const float*)d_in[9];  const float* enbt = (const float*)d_in[10];
  const float* eeW0 = (const float*)d_in[11]; const float* eeb0 = (const float*)d_in[12];
  const float* eeW1 = (const float*)d_in[13]; const float* eeb1 = (const float*)d_in[14];
  const float* eeW2 = (const float*)d_in[15]; const float* eeb2 = (const float*)d_in[16];
  const float* eeg  = (const float*)d_in[17]; const float* eebt = (const float*)d_in[18];
  const float* peW0 = (const float*)d_in[19]; const float* peb0 = (const float*)d_in[20];
  const float* peW1 = (const float*)d_in[21]; const float* peb1 = (const float*)d_in[22];
  const float* peW2 = (const float*)d_in[23]; const float* peb2 = (const float*)d_in[24];
  const float* peg  = (const float*)d_in[25]; const float* pebt = (const float*)d_in[26];
  const float* pnW0 = (const float*)d_in[27]; const float* pnb0 = (const float*)d_in[28];
  const float* pnW1 = (const float*)d_in[29]; const float* pnb1 = (const float*)d_in[30];
  const float* pnW2 = (const float*)d_in[31]; const float* pnb2 = (const float*)d_in[32];
  const float* png  = (const float*)d_in[33]; const float* pnbt = (const float*)d_in[34];
  const float* dW0  = (const float*)d_in[35]; const float* db0  = (const float*)d_in[36];
  const float* dW1  = (const float*)d_in[37]; const float* db1  = (const float*)d_in[38];
  const float* dW2  = (const float*)d_in[39]; const float* db2  = (const float*)d_in[40];

  const size_t F_HX = (size_t)NN * L, F_HE = (size_t)NE * L;
  const size_t W_PE = 819200, W_PN = 655360, W_EE = 32768;

  float* hx = (float*)d_ws;                              // NN*L fp32
  unsigned short* he_bf  = (unsigned short*)(hx + F_HX); // NE*L bf16
  unsigned short* ue_bf  = he_bf + F_HE;                 // NE*L bf16
  unsigned short* hx_bf  = ue_bf + F_HE;                 // NN*L bf16
  unsigned short* wt_pe  = hx_bf + F_HX;
  unsigned short* wt_pn  = wt_pe + W_PE;
  unsigned short* wt_ee  = wt_pn + W_PN;
  int* cnt = (int*)(wt_ee + W_EE);
  int* off = cnt + NN;
  int* cur = off + NN + 1;
  int* eid = cur + NN;

  dim3 blk(256);
  int grid_n64 = (NN + 63) / 64;   // 157 (encoder/decoder)
  int grid_n32 = (NN + 31) / 32;   // 313 (node step)
  int grid_e   = (NE + 63) / 64;   // 1563

  wprep_kernel<<<(10 * 81920 + 255) / 256, blk, 0, stream>>>(peW0, peW1, peW2, wt_pe, 384, 10);
  wprep_kernel<<<(10 * 65536 + 255) / 256, blk, 0, stream>>>(pnW0, pnW1, pnW2, wt_pn, 256, 10);
  tprep_kernel<<<128, blk, 0, stream>>>(eeW1, eeW2, wt_ee);

  hipMemsetAsync(cnt, 0, (size_t)NN * 4, stream);
  deg_kernel<<<(NE + 255) / 256, blk, 0, stream>>>(ei, cnt);
  scan_kernel<<<1, blk, 0, stream>>>(cnt, off, cur);
  scatter_kernel<<<(NE + 255) / 256, blk, 0, stream>>>(ei, cur, eid);

  enc_node_kernel<<<grid_n64, blk, 0, stream>>>(x, enW0, enb0, enW1, enb1, enW2, enb2, eng, enbt, hx, hx_bf);
  enc_edge_mfma<<<grid_e, blk, 0, stream>>>(ea, eeW0, eeb0, wt_ee, eeb1, wt_ee + 16384, eeb2, eeg, eebt, he_bf);

  for (int s = 0; s < STEPS; ++s) {
    const unsigned short* pe = wt_pe + (size_t)s * 81920;
    const unsigned short* pn = wt_pn + (size_t)s * 65536;
    edge_step_mfma<<<grid_e, blk, 0, stream>>>(
        hx_bf, he_bf, ue_bf, ei,
        pe,                 peb0 + (size_t)s * L,
        pe + 49152,         peb1 + (size_t)s * L,
        pe + 49152 + 16384, peb2 + (size_t)s * L,
        peg + (size_t)s * L, pebt + (size_t)s * L);
    node_step_mfma<<<grid_n32, blk, 0, stream>>>(
        hx, hx_bf, ue_bf, off, eid,
        pn,                 pnb0 + (size_t)s * L,
        pn + 32768,         pnb1 + (size_t)s * L,
        pn + 32768 + 16384, pnb2 + (size_t)s * L,
        png + (size_t)s * L, pnbt + (size_t)s * L);
  }

  dec_kernel<<<grid_n64, blk, 0, stream>>>(hx, dW0, db0, dW1, db1, dW2, db2, (float*)d_out);
}